// Round 2
// baseline (785.415 us; speedup 1.0000x reference)
//
#include <hip/hip_runtime.h>
#include <math.h>

#define LSEQ 2048
#define BB 4
#define DD 256
#define NROWS (BB*LSEQ)   // 8192
#define KNB 32

__device__ __forceinline__ float gelu_f(float x){
    return 0.5f*x*(1.0f+erff(x*0.70710678118654752440f));
}
__device__ __forceinline__ float phi_f(float z){   // elu(z)+1
    return z>0.f ? z+1.f : expf(z);
}

// ---------------- LayerNorm (row-wise, D=256, one block per row) -------------
__global__ __launch_bounds__(256) void ln_kernel(
    const float* __restrict__ x, const float* __restrict__ g,
    const float* __restrict__ b, float* __restrict__ out)
{
    int r = blockIdx.x; int t = threadIdx.x;
    size_t i = (size_t)r*DD + t;
    float v = x[i];
    float s = v, ss = v*v;
    #pragma unroll
    for (int o=32;o>=1;o>>=1){ s += __shfl_xor(s,o); ss += __shfl_xor(ss,o); }
    __shared__ float sh[8];
    int wave = t>>6, lane = t&63;
    if (lane==0){ sh[wave]=s; sh[4+wave]=ss; }
    __syncthreads();
    float S  = sh[0]+sh[1]+sh[2]+sh[3];
    float SS = sh[4]+sh[5]+sh[6]+sh[7];
    float mu  = S*(1.f/DD);
    float var = SS*(1.f/DD) - mu*mu;
    float inv = rsqrtf(var + 1e-5f);
    out[i] = (v-mu)*inv*g[t] + b[t];
}

// ---------------- generic fp32 GEMM: C = act(A@W + bias [+ Cold]) ------------
// 64x64 tile, K-step 16, 256 threads, 4x4 micro-tile per thread.
// ACT: 0 none, 1 gelu, 2 sigmoid.  FINAL: C = (addsrc + v) * rowmask
template<int ACT, bool ACCUM, bool FINAL>
__global__ __launch_bounds__(256) void gemm_kernel(
    const float* __restrict__ A, int lda,
    const float* __restrict__ W, int ldw,
    const float* __restrict__ bias,
    float* __restrict__ C, int ldc,
    int Kd,
    const float* __restrict__ addsrc, const int* __restrict__ rowmask)
{
    __shared__ float As[16][64];
    __shared__ float Wsh[16][64];
    int t = threadIdx.x;
    int tx = t & 15, ty = t >> 4;
    int row0 = blockIdx.y*64, col0 = blockIdx.x*64;
    int la_row = t >> 2, la_k = (t & 3)*4;
    int lw_k = t >> 4,  lw_m = (t & 15)*4;
    float acc[4][4] = {};
    for (int k0=0;k0<Kd;k0+=16){
        float4 av = *(const float4*)(A + (size_t)(row0+la_row)*lda + k0 + la_k);
        As[la_k  ][la_row] = av.x;
        As[la_k+1][la_row] = av.y;
        As[la_k+2][la_row] = av.z;
        As[la_k+3][la_row] = av.w;
        *(float4*)&Wsh[lw_k][lw_m] = *(const float4*)(W + (size_t)(k0+lw_k)*ldw + col0 + lw_m);
        __syncthreads();
        #pragma unroll
        for (int k=0;k<16;++k){
            float4 a4 = *(float4*)&As[k][ty*4];
            float4 b4 = *(float4*)&Wsh[k][tx*4];
            acc[0][0]+=a4.x*b4.x; acc[0][1]+=a4.x*b4.y; acc[0][2]+=a4.x*b4.z; acc[0][3]+=a4.x*b4.w;
            acc[1][0]+=a4.y*b4.x; acc[1][1]+=a4.y*b4.y; acc[1][2]+=a4.y*b4.z; acc[1][3]+=a4.y*b4.w;
            acc[2][0]+=a4.z*b4.x; acc[2][1]+=a4.z*b4.y; acc[2][2]+=a4.z*b4.z; acc[2][3]+=a4.z*b4.w;
            acc[3][0]+=a4.w*b4.x; acc[3][1]+=a4.w*b4.y; acc[3][2]+=a4.w*b4.z; acc[3][3]+=a4.w*b4.w;
        }
        __syncthreads();
    }
    #pragma unroll
    for (int i=0;i<4;++i){
        int r = row0 + ty*4 + i;
        float* cp = C + (size_t)r*ldc + col0 + tx*4;
        float4 v;
        v.x = acc[i][0]; v.y = acc[i][1]; v.z = acc[i][2]; v.w = acc[i][3];
        if (bias){
            const float* bp = bias + col0 + tx*4;
            v.x += bp[0]; v.y += bp[1]; v.z += bp[2]; v.w += bp[3];
        }
        if (ACCUM){
            float4 old = *(float4*)cp;
            v.x += old.x; v.y += old.y; v.z += old.z; v.w += old.w;
        }
        if (ACT==1){ v.x=gelu_f(v.x); v.y=gelu_f(v.y); v.z=gelu_f(v.z); v.w=gelu_f(v.w); }
        else if (ACT==2){
            v.x=1.f/(1.f+expf(-v.x)); v.y=1.f/(1.f+expf(-v.y));
            v.z=1.f/(1.f+expf(-v.z)); v.w=1.f/(1.f+expf(-v.w));
        }
        if (FINAL){
            float mf = (float)rowmask[r];
            const float* xp = addsrc + (size_t)r*ldc + col0 + tx*4;
            v.x = (xp[0]+v.x)*mf; v.y = (xp[1]+v.y)*mf;
            v.z = (xp[2]+v.z)*mf; v.w = (xp[3]+v.w)*mf;
        }
        *(float4*)cp = v;
    }
}

// ------------- rel-pos bias table: tab[r] = gelu(emb[r]@we1+be1)@we2+be2 -----
__global__ __launch_bounds__(256) void bias_tab_kernel(
    const float* __restrict__ emb, const float* __restrict__ we1,
    const float* __restrict__ be1, const float* __restrict__ we2,
    const float* __restrict__ be2, float* __restrict__ tab)
{
    int r = blockIdx.x; int j = threadIdx.x;
    float acc = be1[j];
    #pragma unroll 8
    for (int d=0; d<64; ++d) acc += emb[r*64+d]*we1[d*256+j];
    float tv = gelu_f(acc)*we2[j];
    #pragma unroll
    for (int o=32;o>=1;o>>=1) tv += __shfl_xor(tv,o);
    __shared__ float sh[4];
    int wave = j>>6, lane = j&63;
    if (lane==0) sh[wave]=tv;
    __syncthreads();
    if (j==0) tab[r] = sh[0]+sh[1]+sh[2]+sh[3] + be2[0];
}

// ------------- neighbor attention: one block (4 waves) per (b,l) -------------
// nb rows: [q(256) | k(256) | v(256)]
__global__ __launch_bounds__(256) void nattn_kernel(
    const float* __restrict__ nb,
    const int* __restrict__ nbr_idx, const int* __restrict__ nbr_mask,
    const int* __restrict__ rel_pos, const int* __restrict__ mask,
    const float* __restrict__ btab, float* __restrict__ agg)
{
    int r = blockIdx.x;
    int b = r >> 11;                    // L = 2048
    int t = threadIdx.x, lane = t&63, wave = t>>6;
    __shared__ float s_w[32];
    __shared__ int   s_idx[32];
    __shared__ float s_agg[4][256];
    float4 qv = *(const float4*)&nb[(size_t)r*768 + lane*4];
    int mrow = mask[r];
    #pragma unroll
    for (int j=0;j<8;++j){
        int k = wave*8 + j;
        int idx = nbr_idx[r*32+k];
        size_t grow = ((size_t)(b<<11) + idx)*768;
        float4 kv4 = *(const float4*)&nb[grow + 256 + lane*4];
        float d = qv.x*kv4.x + qv.y*kv4.y + qv.z*kv4.z + qv.w*kv4.w;
        #pragma unroll
        for (int o=32;o>=1;o>>=1) d += __shfl_xor(d,o);
        if (lane==0){
            int rp = rel_pos[r*32+k];
            rp = rp < -32 ? -32 : (rp > 32 ? 32 : rp);
            float logit = d*0.0625f + btab[rp+32];
            int am = nbr_mask[r*32+k] * mrow;
            s_w[k]  = am ? logit : -3.402823466e38f;
            s_idx[k] = idx;
        }
    }
    __syncthreads();
    if (wave==0){
        float l = (lane<32) ? s_w[lane] : -3.402823466e38f;
        float m = l;
        #pragma unroll
        for (int o=16;o>=1;o>>=1) m = fmaxf(m, __shfl_xor(m,o));
        float e = (lane<32) ? expf(l-m) : 0.f;
        float ssum = e;
        #pragma unroll
        for (int o=16;o>=1;o>>=1) ssum += __shfl_xor(ssum,o);
        if (lane<32) s_w[lane] = e/ssum;
    }
    __syncthreads();
    float4 av = {0.f,0.f,0.f,0.f};
    #pragma unroll
    for (int j=0;j<8;++j){
        int k = wave*8 + j;
        float wk = s_w[k];
        size_t grow = ((size_t)(b<<11) + s_idx[k])*768;
        float4 vv = *(const float4*)&nb[grow + 512 + lane*4];
        av.x += wk*vv.x; av.y += wk*vv.y; av.z += wk*vv.z; av.w += wk*vv.w;
    }
    *(float4*)&s_agg[wave][lane*4] = av;
    __syncthreads();
    float sum = s_agg[0][t]+s_agg[1][t]+s_agg[2][t]+s_agg[3][t];
    agg[(size_t)r*256 + t] = sum;
}

// ------------- linear-attn stats: kv[b,h,32,32], ksum[b,h,32] ----------------
// NOTE: phi applies to q,k ONLY; v is just masked (reference: vg = vg * m).
__global__ __launch_bounds__(256) void linstats_kernel(
    const float* __restrict__ qkv, const int* __restrict__ mask,
    float* __restrict__ kv, float* __restrict__ ksum)
{
    const int CH = 16, ROWS = LSEQ/CH;       // 128 rows per chunk
    int blk = blockIdx.x;
    int bh = blk / CH, ch = blk % CH;
    int b = bh >> 3, hh = bh & 7;
    int t = threadIdx.x;
    int d = t >> 3, m4 = (t & 7)*4;
    __shared__ float skg[32], svg[32];
    float a0=0,a1=0,a2=0,a3=0, aks=0;
    for (int i=0;i<ROWS;++i){
        int l = ch*ROWS + i;
        size_t base = ((size_t)b*LSEQ + l)*768;
        float mf = (float)mask[b*LSEQ + l];
        if (t < 32)      skg[t]    = phi_f(qkv[base + 256 + hh*32 + t]) * mf;
        else if (t < 64) svg[t-32] = qkv[base + 512 + hh*32 + (t-32)] * mf;   // no phi on V
        __syncthreads();
        float kd = skg[d];
        a0 += kd*svg[m4]; a1 += kd*svg[m4+1]; a2 += kd*svg[m4+2]; a3 += kd*svg[m4+3];
        if ((t&7)==0) aks += kd;
        __syncthreads();
    }
    size_t kb = ((size_t)(b*8+hh)*32 + d)*32 + m4;
    atomicAdd(&kv[kb+0], a0); atomicAdd(&kv[kb+1], a1);
    atomicAdd(&kv[kb+2], a2); atomicAdd(&kv[kb+3], a3);
    if ((t&7)==0) atomicAdd(&ksum[(b*8+hh)*32+d], aks);
}

// ------------- linear-attn apply: y[b,l,h*32+m] ------------------------------
__global__ __launch_bounds__(256) void linapply_kernel(
    const float* __restrict__ qkv, const float* __restrict__ kv,
    const float* __restrict__ ksum, float* __restrict__ y)
{
    int r = blockIdx.x; int b = r >> 11;
    int t = threadIdx.x; int hh = t>>5, m = t&31;
    size_t qb = (size_t)r*768 + hh*32;
    const float* kvb = &kv[((size_t)(b*8+hh)*32)*32 + m];
    const float* ksb = &ksum[(b*8+hh)*32];
    float acc=0.f, az=0.f;
    #pragma unroll
    for (int d=0; d<32; ++d){
        float qd = phi_f(qkv[qb+d]);
        acc += qd * kvb[d*32];
        az  += qd * ksb[d];
    }
    float z = 1.f/(az + 1e-6f);
    y[(size_t)r*256 + t] = acc*z;
}

// ------------- fw = softmax2(f1 @ wf2 + bf2) ---------------------------------
__global__ __launch_bounds__(64) void fw_kernel(
    const float* __restrict__ f1, const float* __restrict__ wf2,
    const float* __restrict__ bf2, float* __restrict__ fw)
{
    int r = blockIdx.x; int lane = threadIdx.x;
    float p0=0.f, p1=0.f;
    #pragma unroll
    for (int j=0;j<4;++j){
        int dd = lane*4 + j;
        float v = f1[(size_t)r*256 + dd];
        p0 += v*wf2[dd*2]; p1 += v*wf2[dd*2+1];
    }
    #pragma unroll
    for (int o=32;o>=1;o>>=1){ p0 += __shfl_xor(p0,o); p1 += __shfl_xor(p1,o); }
    if (lane==0){
        float a0=p0+bf2[0], a1=p1+bf2[1];
        float mx = fmaxf(a0,a1);
        float e0=expf(a0-mx), e1=expf(a1-mx);
        float s = e0+e1;
        fw[r*2] = e0/s; fw[r*2+1] = e1/s;
    }
}

// ------------- combine: x2 = fw0*h_local + fw1*h_global; hn = LN(x2) ---------
__global__ __launch_bounds__(256) void combine_kernel(
    const float* __restrict__ h, const float* __restrict__ agglo,
    const float* __restrict__ g, const float* __restrict__ ygo,
    const float* __restrict__ fw, const int* __restrict__ mask,
    const float* __restrict__ g2, const float* __restrict__ b2,
    float* __restrict__ x2, float* __restrict__ hn)
{
    int r = blockIdx.x, t = threadIdx.x;
    size_t i = (size_t)r*DD + t;
    float mf = (float)mask[r];
    float hv = h[i];
    float hl = (hv + g[i]*agglo[i]) * mf;
    float hg = hv + ygo[i]*mf;
    float f0 = fw[r*2], f1v = fw[r*2+1];
    float v = f0*hl + f1v*hg;
    x2[i] = v;
    float s = v, ss = v*v;
    #pragma unroll
    for (int o=32;o>=1;o>>=1){ s += __shfl_xor(s,o); ss += __shfl_xor(ss,o); }
    __shared__ float sh[8];
    int wave = t>>6, lane = t&63;
    if (lane==0){ sh[wave]=s; sh[4+wave]=ss; }
    __syncthreads();
    float S  = sh[0]+sh[1]+sh[2]+sh[3];
    float SS = sh[4]+sh[5]+sh[6]+sh[7];
    float mu  = S*(1.f/DD);
    float var = SS*(1.f/DD) - mu*mu;
    float inv = rsqrtf(var + 1e-5f);
    hn[i] = (v-mu)*inv*g2[t] + b2[t];
}

// =============================================================================
extern "C" void kernel_launch(void* const* d_in, const int* in_sizes, int n_in,
                              void* d_out, int out_size, void* d_ws, size_t ws_size,
                              hipStream_t stream)
{
    const float* x        = (const float*)d_in[0];
    const int*   mask     = (const int*)  d_in[1];
    const int*   nbr_idx  = (const int*)  d_in[2];
    const int*   nbr_mask = (const int*)  d_in[3];
    const int*   rel_pos  = (const int*)  d_in[4];
    const float* g1   = (const float*)d_in[5];
    const float* b1   = (const float*)d_in[6];
    const float* wq   = (const float*)d_in[7];
    const float* wk   = (const float*)d_in[8];
    const float* wv   = (const float*)d_in[9];
    const float* relpos_emb = (const float*)d_in[10];
    const float* we1  = (const float*)d_in[11];
    const float* be1  = (const float*)d_in[12];
    const float* we2  = (const float*)d_in[13];
    const float* be2  = (const float*)d_in[14];
    const float* wg1  = (const float*)d_in[15];
    const float* bg1  = (const float*)d_in[16];
    const float* wg2  = (const float*)d_in[17];
    const float* bg2  = (const float*)d_in[18];
    const float* wlo  = (const float*)d_in[19];
    const float* blo  = (const float*)d_in[20];
    const float* wqkv = (const float*)d_in[21];
    const float* wgo  = (const float*)d_in[22];
    const float* wf1  = (const float*)d_in[23];
    const float* bf1  = (const float*)d_in[24];
    const float* wf2  = (const float*)d_in[25];
    const float* bf2  = (const float*)d_in[26];
    const float* g2   = (const float*)d_in[27];
    const float* b2   = (const float*)d_in[28];
    const float* wff1 = (const float*)d_in[29];
    const float* bff1 = (const float*)d_in[30];
    const float* wff2 = (const float*)d_in[31];
    const float* bff2 = (const float*)d_in[32];
    float* out = (float*)d_out;

    float* ws = (float*)d_ws;
    const size_t U = (size_t)NROWS * DD;   // 2,097,152 floats
    float* h      = ws;                    // U0
    float* nb     = ws + U;                // U1..U3: [hq|hk|hv] rows, later qkv
    float* aggv   = ws + 4*U;              // agg -> g
    float* agglo  = ws + 5*U;
    float* t1     = ws + 6*U;              // t1 -> y -> x2
    float* f1     = ws + 7*U;              // f1 -> hn
    float* ygo    = ws + U;                // reuse (nb dead after linapply)
    float* fchunk = ws + 2*U;              // reuse
    float* smallb = ws + 8*U;
    float* btab = smallb;                          // 128
    float* kvb  = smallb + 128;                    // 32768
    float* ksb  = smallb + 128 + 32768;            // 1024
    float* fwb  = smallb + 128 + 32768 + 1024;     // 16384

    dim3 blk(256);
    dim3 g256(4, NROWS/64);
    dim3 g768(12, NROWS/64);

    // 1. h = LN(x)*g1 + b1
    ln_kernel<<<NROWS, blk, 0, stream>>>(x, g1, b1, h);
    // 2. nb = [h@wq | h@wk | h@wv]   (ldc = 768)
    gemm_kernel<0,false,false><<<g256, blk, 0, stream>>>(h,256, wq,256, nullptr, nb+0,  768, 256, nullptr, nullptr);
    gemm_kernel<0,false,false><<<g256, blk, 0, stream>>>(h,256, wk,256, nullptr, nb+256,768, 256, nullptr, nullptr);
    gemm_kernel<0,false,false><<<g256, blk, 0, stream>>>(h,256, wv,256, nullptr, nb+512,768, 256, nullptr, nullptr);
    // 3. rel-pos bias table (65 entries)
    bias_tab_kernel<<<65, blk, 0, stream>>>(relpos_emb, we1, be1, we2, be2, btab);
    // 4. neighbor attention -> agg
    nattn_kernel<<<NROWS, blk, 0, stream>>>(nb, nbr_idx, nbr_mask, rel_pos, mask, btab, aggv);
    // 5. agglo = agg@wlo + blo
    gemm_kernel<0,false,false><<<g256, blk, 0, stream>>>(aggv,256, wlo,256, blo, agglo,256, 256, nullptr, nullptr);
    // 6. t1 = gelu(h@wg1_top + bg1 + agglo@wg1_bot)
    gemm_kernel<0,false,false><<<g256, blk, 0, stream>>>(h,256,     wg1,256,         bg1,     t1,256, 256, nullptr, nullptr);
    gemm_kernel<1,true ,false><<<g256, blk, 0, stream>>>(agglo,256, wg1+256*256,256, nullptr, t1,256, 256, nullptr, nullptr);
    // 7. g = sigmoid(t1@wg2 + bg2)   (overwrites agg slot)
    gemm_kernel<2,false,false><<<g256, blk, 0, stream>>>(t1,256, wg2,256, bg2, aggv,256, 256, nullptr, nullptr);
    // 8. qkv = h@wqkv  (reuse nb)
    gemm_kernel<0,false,false><<<g768, blk, 0, stream>>>(h,256, wqkv,768, nullptr, nb,768, 256, nullptr, nullptr);
    // 9. linear attention
    hipMemsetAsync(kvb, 0, (32768+1024)*sizeof(float), stream);
    linstats_kernel<<<512, blk, 0, stream>>>(nb, mask, kvb, ksb);
    linapply_kernel<<<NROWS, blk, 0, stream>>>(nb, kvb, ksb, t1);   // y in t1
    // 10. ygo = y@wgo
    gemm_kernel<0,false,false><<<g256, blk, 0, stream>>>(t1,256, wgo,256, nullptr, ygo,256, 256, nullptr, nullptr);
    // 11. f1 = gelu(h@wf1 + bf1); fw = softmax2(f1@wf2+bf2)
    gemm_kernel<1,false,false><<<g256, blk, 0, stream>>>(h,256, wf1,256, bf1, f1,256, 256, nullptr, nullptr);
    fw_kernel<<<NROWS, dim3(64), 0, stream>>>(f1, wf2, bf2, fwb);
    // 12. combine -> x2 (t1 slot), hn (f1 slot)
    combine_kernel<<<NROWS, blk, 0, stream>>>(h, agglo, aggv, ygo, fwb, mask, g2, b2, t1, f1);
    // 13. FFN in 4 column-chunks of 256; accumulate into out; final epilogue adds x2 and masks
    for (int c=0;c<4;++c){
        gemm_kernel<1,false,false><<<g256, blk, 0, stream>>>(f1,256, wff1 + c*256, 1024, bff1 + c*256, fchunk,256, 256, nullptr, nullptr);
        if (c==0)
            gemm_kernel<0,false,false><<<g256, blk, 0, stream>>>(fchunk,256, wff2 + (size_t)c*256*256, 256, bff2, out,256, 256, nullptr, nullptr);
        else if (c<3)
            gemm_kernel<0,true ,false><<<g256, blk, 0, stream>>>(fchunk,256, wff2 + (size_t)c*256*256, 256, nullptr, out,256, 256, nullptr, nullptr);
        else
            gemm_kernel<0,true ,true ><<<g256, blk, 0, stream>>>(fchunk,256, wff2 + (size_t)c*256*256, 256, nullptr, out,256, 256, t1, mask);
    }
}

// Round 3
// 345.712 us; speedup vs baseline: 2.2719x; 2.2719x over previous
//
#include <hip/hip_runtime.h>
#include <math.h>

#define LSEQ 2048
#define BB 4
#define DD 256
#define NROWS (BB*LSEQ)   // 8192

typedef unsigned short u16;
typedef unsigned int u32;
typedef short s16x8 __attribute__((ext_vector_type(8)));
typedef float f32x4 __attribute__((ext_vector_type(4)));

__device__ __forceinline__ float gelu_f(float x){
    return 0.5f*x*(1.0f+erff(x*0.70710678118654752440f));
}
__device__ __forceinline__ float phi_f(float z){ return z>0.f ? z+1.f : expf(z); }
__device__ __forceinline__ float bf2f(u16 u){ union{u32 i; float f;} x; x.i = ((u32)u)<<16; return x.f; }
__device__ __forceinline__ u16 f2bf(float f){ union{float f; u32 i;} x; x.f = f; u32 r = (x.i + 0x7fff + ((x.i>>16)&1)) >> 16; return (u16)r; }

// ---------------- weight transpose+cvt: WT[n][k] = bf16(W[k][n]) -------------
struct TransDesc { const float* src; int dstoff; int K; int N; };
struct TransArgs { TransDesc d[11]; };

__global__ __launch_bounds__(256) void transpose_kernel(TransArgs args, u16* __restrict__ WT)
{
    TransDesc e = args.d[blockIdx.z];
    int kt = blockIdx.x, nt = blockIdx.y;
    if (kt*32 >= e.K || nt*32 >= e.N) return;
    __shared__ float tile[32][33];
    int tx = threadIdx.x & 31, ty = threadIdx.x >> 5;
    #pragma unroll
    for (int i=0;i<4;++i){
        int k = kt*32 + ty + i*8;
        tile[ty+i*8][tx] = e.src[(size_t)k*e.N + nt*32 + tx];
    }
    __syncthreads();
    #pragma unroll
    for (int i=0;i<4;++i){
        int n = nt*32 + ty + i*8;
        WT[e.dstoff + (size_t)n*e.K + kt*32 + tx] = f2bf(tile[tx][ty+i*8]);
    }
}

// ---------------- LayerNorm: fp32 in -> bf16 out -----------------------------
__global__ __launch_bounds__(256) void ln_kernel(
    const float* __restrict__ x, const float* __restrict__ g,
    const float* __restrict__ b, u16* __restrict__ out)
{
    int r = blockIdx.x; int t = threadIdx.x;
    size_t i = (size_t)r*DD + t;
    float v = x[i];
    float s = v, ss = v*v;
    #pragma unroll
    for (int o=32;o>=1;o>>=1){ s += __shfl_xor(s,o); ss += __shfl_xor(ss,o); }
    __shared__ float sh[8];
    int wave = t>>6, lane = t&63;
    if (lane==0){ sh[wave]=s; sh[4+wave]=ss; }
    __syncthreads();
    float S  = sh[0]+sh[1]+sh[2]+sh[3];
    float SS = sh[4]+sh[5]+sh[6]+sh[7];
    float mu  = S*(1.f/DD);
    float var = SS*(1.f/DD) - mu*mu;
    float inv = rsqrtf(var + 1e-5f);
    out[i] = f2bf((v-mu)*inv*g[t] + b[t]);
}

// ---------------- MFMA bf16 GEMM: C = act([A0|A1]@WT^T + bias) ---------------
// BM=64, BN=128, BK=32; 256 threads = 4 waves (2x2), wave tile 32x64.
// A bf16 row-major [M][lda]; WT bf16 [N][Kd] (i.e. W transposed).
// LDS frag layout: per 16-row block & k-octet, 16 lanes x 16B, lane-linear reads.
template<int ACT, bool FINAL, typename CT>
__global__ __launch_bounds__(256) void mgemm(
    const u16* __restrict__ A0, const u16* __restrict__ A1, int kswitch, int lda,
    const u16* __restrict__ WT, int Kd,
    const float* __restrict__ bias,
    CT* __restrict__ C, int ldc,
    const u16* __restrict__ addsrc, const int* __restrict__ rowmask)
{
    __shared__ u16 ldsA[2048];   // 64 rows x 32 k
    __shared__ u16 ldsB[4096];   // 128 cols x 32 k
    int t = threadIdx.x;
    int row0 = blockIdx.x*64, col0 = blockIdx.y*128;
    int l = t & 63, w = t >> 6;
    int wm = w >> 1, wn = w & 1;

    int ar = t >> 2, ao = t & 3;
    int aidx = (ar>>4)*512 + ao*128 + (ar&15)*8;
    int bc0 = t >> 2, bo = t & 3;
    int bidx0 = (bc0>>4)*512 + bo*128 + (bc0&15)*8;
    int bc1 = bc0 + 64;
    int bidx1 = (bc1>>4)*512 + bo*128 + (bc1&15)*8;

    f32x4 acc[2][4];
    #pragma unroll
    for (int mf=0;mf<2;++mf)
        #pragma unroll
        for (int nf=0;nf<4;++nf)
            acc[mf][nf] = (f32x4){0.f,0.f,0.f,0.f};

    for (int k0 = 0; k0 < Kd; k0 += 32){
        const u16* Ab = A0; int kk = k0;
        if (k0 >= kswitch){ Ab = A1; kk = k0 - kswitch; }
        uint4 av  = *(const uint4*)(Ab + (size_t)(row0+ar)*lda + kk + ao*8);
        uint4 bv0 = *(const uint4*)(WT + (size_t)(col0+bc0)*Kd + k0 + bo*8);
        uint4 bv1 = *(const uint4*)(WT + (size_t)(col0+bc1)*Kd + k0 + bo*8);
        __syncthreads();
        *(uint4*)&ldsA[aidx]  = av;
        *(uint4*)&ldsB[bidx0] = bv0;
        *(uint4*)&ldsB[bidx1] = bv1;
        __syncthreads();
        s16x8 af[2], bfr[4];
        #pragma unroll
        for (int mf=0;mf<2;++mf) af[mf] = *(s16x8*)&ldsA[(wm*2+mf)*512 + l*8];
        #pragma unroll
        for (int nf=0;nf<4;++nf) bfr[nf] = *(s16x8*)&ldsB[(wn*4+nf)*512 + l*8];
        #pragma unroll
        for (int mf=0; mf<2; ++mf)
            #pragma unroll
            for (int nf=0; nf<4; ++nf)
                acc[mf][nf] = __builtin_amdgcn_mfma_f32_16x16x32_bf16(af[mf], bfr[nf], acc[mf][nf], 0,0,0);
    }

    int lrow = (l>>4)*4, lcol = l&15;
    #pragma unroll
    for (int mf=0; mf<2; ++mf){
        #pragma unroll
        for (int nf=0; nf<4; ++nf){
            int col = col0 + wn*64 + nf*16 + lcol;
            float bv = bias ? bias[col] : 0.f;
            #pragma unroll
            for (int i=0;i<4;++i){
                int row = row0 + wm*32 + mf*16 + lrow + i;
                float v = acc[mf][nf][i] + bv;
                if (ACT==1) v = gelu_f(v);
                else if (ACT==2) v = 1.f/(1.f+expf(-v));
                if (FINAL){
                    float mfv = (float)rowmask[row];
                    v = (bf2f(addsrc[(size_t)row*ldc + col]) + v) * mfv;
                }
                if constexpr (sizeof(CT)==2) C[(size_t)row*ldc+col] = (CT)f2bf(v);
                else                         C[(size_t)row*ldc+col] = v;
            }
        }
    }
}

// ------------- rel-pos bias table (fp32 weights) -----------------------------
__global__ __launch_bounds__(256) void bias_tab_kernel(
    const float* __restrict__ emb, const float* __restrict__ we1,
    const float* __restrict__ be1, const float* __restrict__ we2,
    const float* __restrict__ be2, float* __restrict__ tab)
{
    int r = blockIdx.x; int j = threadIdx.x;
    float acc = be1[j];
    #pragma unroll 8
    for (int d=0; d<64; ++d) acc += emb[r*64+d]*we1[d*256+j];
    float tv = gelu_f(acc)*we2[j];
    #pragma unroll
    for (int o=32;o>=1;o>>=1) tv += __shfl_xor(tv,o);
    __shared__ float sh[4];
    int wave = j>>6, lane = j&63;
    if (lane==0) sh[wave]=tv;
    __syncthreads();
    if (j==0) tab[r] = sh[0]+sh[1]+sh[2]+sh[3] + be2[0];
}

// ------------- neighbor attention (bf16 nb) ----------------------------------
__global__ __launch_bounds__(256) void nattn_kernel(
    const u16* __restrict__ nb,
    const int* __restrict__ nbr_idx, const int* __restrict__ nbr_mask,
    const int* __restrict__ rel_pos, const int* __restrict__ mask,
    const float* __restrict__ btab, u16* __restrict__ agg)
{
    int r = blockIdx.x;
    int b = r >> 11;
    int t = threadIdx.x, lane = t&63, wave = t>>6;
    __shared__ float s_w[32];
    __shared__ int   s_idx[32];
    __shared__ float s_agg[4][256];
    uint2 qu = *(const uint2*)&nb[(size_t)r*768 + lane*4];
    float q0 = bf2f(qu.x&0xffff), q1 = bf2f(qu.x>>16);
    float q2 = bf2f(qu.y&0xffff), q3 = bf2f(qu.y>>16);
    int mrow = mask[r];
    #pragma unroll
    for (int j=0;j<8;++j){
        int k = wave*8 + j;
        int idx = nbr_idx[r*32+k];
        size_t grow = ((size_t)(b<<11) + idx)*768;
        uint2 ku = *(const uint2*)&nb[grow + 256 + lane*4];
        float d = q0*bf2f(ku.x&0xffff) + q1*bf2f(ku.x>>16)
                + q2*bf2f(ku.y&0xffff) + q3*bf2f(ku.y>>16);
        #pragma unroll
        for (int o=32;o>=1;o>>=1) d += __shfl_xor(d,o);
        if (lane==0){
            int rp = rel_pos[r*32+k];
            rp = rp < -32 ? -32 : (rp > 32 ? 32 : rp);
            float logit = d*0.0625f + btab[rp+32];
            int am = nbr_mask[r*32+k] * mrow;
            s_w[k]  = am ? logit : -3.402823466e38f;
            s_idx[k] = idx;
        }
    }
    __syncthreads();
    if (wave==0){
        float lg = (lane<32) ? s_w[lane] : -3.402823466e38f;
        float m = lg;
        #pragma unroll
        for (int o=16;o>=1;o>>=1) m = fmaxf(m, __shfl_xor(m,o));
        float e = (lane<32) ? expf(lg-m) : 0.f;
        float ssum = e;
        #pragma unroll
        for (int o=16;o>=1;o>>=1) ssum += __shfl_xor(ssum,o);
        if (lane<32) s_w[lane] = e/ssum;
    }
    __syncthreads();
    float4 av = {0.f,0.f,0.f,0.f};
    #pragma unroll
    for (int j=0;j<8;++j){
        int k = wave*8 + j;
        float wk = s_w[k];
        size_t grow = ((size_t)(b<<11) + s_idx[k])*768;
        uint2 vu = *(const uint2*)&nb[grow + 512 + lane*4];
        av.x += wk*bf2f(vu.x&0xffff); av.y += wk*bf2f(vu.x>>16);
        av.z += wk*bf2f(vu.y&0xffff); av.w += wk*bf2f(vu.y>>16);
    }
    *(float4*)&s_agg[wave][lane*4] = av;
    __syncthreads();
    float sum = s_agg[0][t]+s_agg[1][t]+s_agg[2][t]+s_agg[3][t];
    agg[(size_t)r*256 + t] = f2bf(sum);
}

// ------------- linear-attn stats (phi on k only; v just masked) --------------
__global__ __launch_bounds__(256) void linstats_kernel(
    const u16* __restrict__ qkv, const int* __restrict__ mask,
    float* __restrict__ kv, float* __restrict__ ksum)
{
    int blk = blockIdx.x;
    int bh = blk >> 4, ch = blk & 15;
    int b = bh >> 3, hh = bh & 7;
    int t = threadIdx.x;
    int d = t >> 3, m4 = (t & 7)*4;
    __shared__ float sk[8][32], sv[8][32];
    float a0=0,a1=0,a2=0,a3=0, aks=0;
    int l0 = ch*128;
    int half = t >> 7, tt = t & 127;
    int lr = tt >> 4, e2 = (tt & 15)*2;
    for (int g8=0; g8<16; ++g8){
        int l = l0 + g8*8 + lr;
        size_t base = ((size_t)b*LSEQ + l)*768 + (half ? 512 : 256) + hh*32 + e2;
        u32 u = *(const u32*)&qkv[base];
        float mf = (float)mask[b*LSEQ + l];
        float x0 = bf2f((u16)(u & 0xffff));
        float x1 = bf2f((u16)(u >> 16));
        if (half==0){ sk[lr][e2] = phi_f(x0)*mf; sk[lr][e2+1] = phi_f(x1)*mf; }
        else        { sv[lr][e2] = x0*mf;        sv[lr][e2+1] = x1*mf; }
        __syncthreads();
        #pragma unroll
        for (int rr=0;rr<8;++rr){
            float kd = sk[rr][d];
            a0 += kd*sv[rr][m4]; a1 += kd*sv[rr][m4+1];
            a2 += kd*sv[rr][m4+2]; a3 += kd*sv[rr][m4+3];
            if ((t&7)==0) aks += kd;
        }
        __syncthreads();
    }
    size_t kb = (size_t)bh*1024 + d*32 + m4;
    atomicAdd(&kv[kb+0],a0); atomicAdd(&kv[kb+1],a1);
    atomicAdd(&kv[kb+2],a2); atomicAdd(&kv[kb+3],a3);
    if ((t&7)==0) atomicAdd(&ksum[bh*32+d], aks);
}

// ------------- linear-attn apply ---------------------------------------------
__global__ __launch_bounds__(256) void linapply_kernel(
    const u16* __restrict__ qkv, const float* __restrict__ kv,
    const float* __restrict__ ksum, u16* __restrict__ y)
{
    int r = blockIdx.x; int b = r >> 11;
    int t = threadIdx.x;
    __shared__ float sq[256];
    if (t < 128){
        u32 u = *(const u32*)&qkv[(size_t)r*768 + t*2];
        sq[t*2]   = phi_f(bf2f((u16)(u & 0xffff)));
        sq[t*2+1] = phi_f(bf2f((u16)(u >> 16)));
    }
    __syncthreads();
    int hh = t>>5, m = t&31;
    const float* kvb = &kv[(size_t)((b<<3)+hh)*1024 + m];
    const float* ksb = &ksum[((b<<3)+hh)*32];
    const float* sqh = &sq[hh*32];
    float acc=0.f, az=0.f;
    #pragma unroll
    for (int dd=0; dd<32; ++dd){
        float qd = sqh[dd];
        acc += qd * kvb[dd*32];
        az  += qd * ksb[dd];
    }
    y[(size_t)r*256 + t] = f2bf(acc / (az + 1e-6f));
}

// ------------- fw = softmax2(f1 @ wf2 + bf2) ---------------------------------
__global__ __launch_bounds__(64) void fw_kernel(
    const u16* __restrict__ f1, const float* __restrict__ wf2,
    const float* __restrict__ bf2, float* __restrict__ fw)
{
    int r = blockIdx.x; int lane = threadIdx.x;
    uint2 fu = *(const uint2*)&f1[(size_t)r*256 + lane*4];
    float v0 = bf2f(fu.x&0xffff), v1 = bf2f(fu.x>>16);
    float v2 = bf2f(fu.y&0xffff), v3 = bf2f(fu.y>>16);
    int dd = lane*4;
    float p0 = v0*wf2[dd*2]   + v1*wf2[dd*2+2] + v2*wf2[dd*2+4] + v3*wf2[dd*2+6];
    float p1 = v0*wf2[dd*2+1] + v1*wf2[dd*2+3] + v2*wf2[dd*2+5] + v3*wf2[dd*2+7];
    #pragma unroll
    for (int o=32;o>=1;o>>=1){ p0 += __shfl_xor(p0,o); p1 += __shfl_xor(p1,o); }
    if (lane==0){
        float a0=p0+bf2[0], a1=p1+bf2[1];
        float mx = fmaxf(a0,a1);
        float e0=expf(a0-mx), e1=expf(a1-mx);
        float s = e0+e1;
        fw[r*2] = e0/s; fw[r*2+1] = e1/s;
    }
}

// ------------- combine: x2 = fw0*h_local + fw1*h_global; hn = LN(x2) ---------
__global__ __launch_bounds__(128) void combine_kernel(
    const u16* __restrict__ h, const u16* __restrict__ agglo,
    const u16* __restrict__ g, const u16* __restrict__ ygo,
    const float* __restrict__ fw, const int* __restrict__ mask,
    const float* __restrict__ g2, const float* __restrict__ b2,
    u16* __restrict__ x2, u16* __restrict__ hn)
{
    int r = blockIdx.x, t = threadIdx.x;
    size_t i = (size_t)r*DD + t*2;
    float mf = (float)mask[r];
    u32 hu = *(const u32*)&h[i],  au = *(const u32*)&agglo[i];
    u32 gu = *(const u32*)&g[i],  yu = *(const u32*)&ygo[i];
    float f0 = fw[r*2], f1v = fw[r*2+1];
    float hv0 = bf2f((u16)(hu&0xffff)), hv1 = bf2f((u16)(hu>>16));
    float ag0 = bf2f((u16)(au&0xffff)), ag1 = bf2f((u16)(au>>16));
    float gg0 = bf2f((u16)(gu&0xffff)), gg1 = bf2f((u16)(gu>>16));
    float yy0 = bf2f((u16)(yu&0xffff)), yy1 = bf2f((u16)(yu>>16));
    float v0 = f0*((hv0 + gg0*ag0)*mf) + f1v*(hv0 + yy0*mf);
    float v1 = f0*((hv1 + gg1*ag1)*mf) + f1v*(hv1 + yy1*mf);
    *(u32*)&x2[i] = (u32)f2bf(v0) | ((u32)f2bf(v1)<<16);
    float s = v0+v1, ss = v0*v0+v1*v1;
    #pragma unroll
    for (int o=32;o>=1;o>>=1){ s += __shfl_xor(s,o); ss += __shfl_xor(ss,o); }
    __shared__ float sh[4];
    int wave = t>>6, lane = t&63;
    if (lane==0){ sh[wave]=s; sh[2+wave]=ss; }
    __syncthreads();
    float S  = sh[0]+sh[1];
    float SS = sh[2]+sh[3];
    float mu  = S*(1.f/DD);
    float var = SS*(1.f/DD) - mu*mu;
    float inv = rsqrtf(var + 1e-5f);
    int j0 = t*2;
    float o0 = (v0-mu)*inv*g2[j0]   + b2[j0];
    float o1 = (v1-mu)*inv*g2[j0+1] + b2[j0+1];
    *(u32*)&hn[i] = (u32)f2bf(o0) | ((u32)f2bf(o1)<<16);
}

// =============================================================================
extern "C" void kernel_launch(void* const* d_in, const int* in_sizes, int n_in,
                              void* d_out, int out_size, void* d_ws, size_t ws_size,
                              hipStream_t stream)
{
    const float* x        = (const float*)d_in[0];
    const int*   mask     = (const int*)  d_in[1];
    const int*   nbr_idx  = (const int*)  d_in[2];
    const int*   nbr_mask = (const int*)  d_in[3];
    const int*   rel_pos  = (const int*)  d_in[4];
    const float* g1   = (const float*)d_in[5];
    const float* b1   = (const float*)d_in[6];
    const float* wq   = (const float*)d_in[7];
    const float* wk   = (const float*)d_in[8];
    const float* wv   = (const float*)d_in[9];
    const float* relpos_emb = (const float*)d_in[10];
    const float* we1  = (const float*)d_in[11];
    const float* be1  = (const float*)d_in[12];
    const float* we2  = (const float*)d_in[13];
    const float* be2  = (const float*)d_in[14];
    const float* wg1  = (const float*)d_in[15];
    const float* bg1  = (const float*)d_in[16];
    const float* wg2  = (const float*)d_in[17];
    const float* bg2  = (const float*)d_in[18];
    const float* wlo  = (const float*)d_in[19];
    const float* blo  = (const float*)d_in[20];
    const float* wqkv = (const float*)d_in[21];
    const float* wgo  = (const float*)d_in[22];
    const float* wf1  = (const float*)d_in[23];
    const float* bf1  = (const float*)d_in[24];
    const float* wf2  = (const float*)d_in[25];
    const float* bf2  = (const float*)d_in[26];
    const float* g2   = (const float*)d_in[27];
    const float* b2   = (const float*)d_in[28];
    const float* wff1 = (const float*)d_in[29];
    const float* bff1 = (const float*)d_in[30];
    const float* wff2 = (const float*)d_in[31];
    const float* bff2 = (const float*)d_in[32];
    float* out = (float*)d_out;

    unsigned char* wsb = (unsigned char*)d_ws;
    u16* h_bf    = (u16*)(wsb + ((size_t)0<<20));
    u16* nb_bf   = (u16*)(wsb + ((size_t)4<<20));
    u16* agg_bf  = (u16*)(wsb + ((size_t)16<<20));
    u16* agglo_bf= (u16*)(wsb + ((size_t)20<<20));
    u16* t1_bf   = (u16*)(wsb + ((size_t)24<<20));
    u16* f1_bf   = (u16*)(wsb + ((size_t)28<<20));
    u16* ygo_bf  = (u16*)(wsb + ((size_t)32<<20));
    u16* ffn1_bf = (u16*)(wsb + ((size_t)36<<20));
    u16* WT      = (u16*)(wsb + ((size_t)52<<20));
    float* btab  = (float*)(wsb + ((size_t)56<<20));  // 65
    float* kvb   = btab + 128;                        // 32768
    float* ksb   = kvb + 32768;                       // 1024
    float* fwb   = ksb + 1024;                        // 16384

    // WT sub-offsets (u16 units)
    const int WT_LOC  = 0;        // [768][256]: wq^T|wk^T|wv^T
    const int WT_LO   = 196608;   // [256][256]
    const int WT_G1   = 262144;   // [256][512]
    const int WT_G2   = 393216;   // [256][256]
    const int WT_QKV  = 458752;   // [768][256]
    const int WT_GO   = 655360;   // [256][256]
    const int WT_F1   = 720896;   // [256][256]
    const int WT_FF1  = 786432;   // [1024][256]
    const int WT_FF2  = 1048576;  // [256][1024]

    TransArgs ta;
    ta.d[0]  = { wq,              WT_LOC,           256, 256 };
    ta.d[1]  = { wk,              WT_LOC + 65536,   256, 256 };
    ta.d[2]  = { wv,              WT_LOC + 131072,  256, 256 };
    ta.d[3]  = { wlo,             WT_LO,            256, 256 };
    ta.d[4]  = { wg1,             WT_G1,            512, 256 };
    ta.d[5]  = { wg2,             WT_G2,            256, 256 };
    ta.d[6]  = { wqkv,            WT_QKV,           256, 768 };
    ta.d[7]  = { wgo,             WT_GO,            256, 256 };
    ta.d[8]  = { wf1,             WT_F1,            256, 256 };
    ta.d[9]  = { wff1,            WT_FF1,           256, 1024 };
    ta.d[10] = { wff2,            WT_FF2,           1024, 256 };

    const int KBIG = 1<<30;
    dim3 blk(256);

    transpose_kernel<<<dim3(32,32,11), blk, 0, stream>>>(ta, WT);
    ln_kernel<<<NROWS, blk, 0, stream>>>(x, g1, b1, h_bf);
    bias_tab_kernel<<<65, blk, 0, stream>>>(relpos_emb, we1, be1, we2, be2, btab);
    // nb = h @ [wq|wk|wv]
    mgemm<0,false,u16><<<dim3(128,6), blk, 0, stream>>>(h_bf, h_bf, KBIG, 256, WT+WT_LOC, 256, nullptr, nb_bf, 768, nullptr, nullptr);
    nattn_kernel<<<NROWS, blk, 0, stream>>>(nb_bf, nbr_idx, nbr_mask, rel_pos, mask, btab, agg_bf);
    // agglo = agg@wlo + blo
    mgemm<0,false,u16><<<dim3(128,2), blk, 0, stream>>>(agg_bf, agg_bf, KBIG, 256, WT+WT_LO, 256, blo, agglo_bf, 256, nullptr, nullptr);
    // t1 = gelu([h|agglo]@wg1 + bg1)
    mgemm<1,false,u16><<<dim3(128,2), blk, 0, stream>>>(h_bf, agglo_bf, 256, 256, WT+WT_G1, 512, bg1, t1_bf, 256, nullptr, nullptr);
    // g = sigmoid(t1@wg2 + bg2) -> agg slot
    mgemm<2,false,u16><<<dim3(128,2), blk, 0, stream>>>(t1_bf, t1_bf, KBIG, 256, WT+WT_G2, 256, bg2, agg_bf, 256, nullptr, nullptr);
    // qkv = h@wqkv -> nb slot
    mgemm<0,false,u16><<<dim3(128,6), blk, 0, stream>>>(h_bf, h_bf, KBIG, 256, WT+WT_QKV, 256, nullptr, nb_bf, 768, nullptr, nullptr);
    // linear attention
    hipMemsetAsync(kvb, 0, (32768+1024)*sizeof(float), stream);
    linstats_kernel<<<512, blk, 0, stream>>>(nb_bf, mask, kvb, ksb);
    linapply_kernel<<<NROWS, blk, 0, stream>>>(nb_bf, kvb, ksb, t1_bf);  // y -> t1
    // ygo = y@wgo
    mgemm<0,false,u16><<<dim3(128,2), blk, 0, stream>>>(t1_bf, t1_bf, KBIG, 256, WT+WT_GO, 256, nullptr, ygo_bf, 256, nullptr, nullptr);
    // f1 = gelu(h@wf1 + bf1)
    mgemm<1,false,u16><<<dim3(128,2), blk, 0, stream>>>(h_bf, h_bf, KBIG, 256, WT+WT_F1, 256, bf1, f1_bf, 256, nullptr, nullptr);
    fw_kernel<<<NROWS, dim3(64), 0, stream>>>(f1_bf, wf2, bf2, fwb);
    // combine -> x2 (t1 slot), hn (f1 slot)
    combine_kernel<<<NROWS, dim3(128), 0, stream>>>(h_bf, agglo_bf, agg_bf, ygo_bf, fwb, mask, g2, b2, t1_bf, f1_bf);
    // ffn1 = gelu(hn@wff1 + bff1)
    mgemm<1,false,u16><<<dim3(128,8), blk, 0, stream>>>(f1_bf, f1_bf, KBIG, 256, WT+WT_FF1, 256, bff1, ffn1_bf, 1024, nullptr, nullptr);
    // out = (x2 + ffn1@wff2 + bff2)*mf
    mgemm<0,true,float><<<dim3(128,2), blk, 0, stream>>>(ffn1_bf, ffn1_bf, KBIG, 1024, WT+WT_FF2, 1024, bff2, out, 256, t1_bf, mask);
}

// Round 5
// 296.644 us; speedup vs baseline: 2.6477x; 1.1654x over previous
//
#include <hip/hip_runtime.h>
#include <math.h>

#define LSEQ 2048
#define BB 4
#define DD 256
#define NROWS (BB*LSEQ)   // 8192
#define LDBIG 1792

typedef unsigned short u16;
typedef unsigned int u32;
typedef short s16x8 __attribute__((ext_vector_type(8)));
typedef float f32x4 __attribute__((ext_vector_type(4)));

__device__ __forceinline__ float gelu_f(float x){
    return 0.5f*x*(1.0f+erff(x*0.70710678118654752440f));
}
__device__ __forceinline__ float phi_f(float z){ return z>0.f ? z+1.f : expf(z); }
__device__ __forceinline__ float bf2f(u16 u){ union{u32 i; float f;} x; x.i = ((u32)u)<<16; return x.f; }
__device__ __forceinline__ u16 f2bf(float f){ union{float f; u32 i;} x; x.f = f; u32 r = (x.i + 0x7fff + ((x.i>>16)&1)) >> 16; return (u16)r; }

// ---------------- weight transpose+cvt: WT[n][k] = bf16(W[k][n]) -------------
struct TransDesc { const float* src; int dstoff; int K; int N; int tstart; };
struct TransArgs { TransDesc d[11]; };

__global__ __launch_bounds__(256) void transpose_kernel(TransArgs args, u16* __restrict__ WT)
{
    int bid = blockIdx.x;
    int z = 0;
    #pragma unroll
    for (int i=1;i<11;++i) if (bid >= args.d[i].tstart) z = i;
    TransDesc e = args.d[z];
    int tid = bid - e.tstart;
    int ntx = e.N >> 5;
    int kt = tid / ntx, nt = tid - kt*ntx;
    __shared__ float tile[32][33];
    int tx = threadIdx.x & 31, ty = threadIdx.x >> 5;
    #pragma unroll
    for (int i=0;i<4;++i){
        int k = kt*32 + ty + i*8;
        tile[ty+i*8][tx] = e.src[(size_t)k*e.N + nt*32 + tx];
    }
    __syncthreads();
    #pragma unroll
    for (int i=0;i<4;++i){
        int n = nt*32 + ty + i*8;
        WT[e.dstoff + (size_t)n*e.K + kt*32 + tx] = f2bf(tile[tx][ty+i*8]);
    }
}

// ---------------- fused bias for big GEMM: [0 x1536 | bf1] -------------------
__global__ __launch_bounds__(256) void biasbig_kernel(const float* __restrict__ bf1, float* __restrict__ bb)
{
    int i = blockIdx.x*256 + threadIdx.x;
    bb[i] = (i >= 1536) ? bf1[i-1536] : 0.f;
}

// ---------------- LayerNorm: fp32 in -> bf16 out -----------------------------
__global__ __launch_bounds__(256) void ln_kernel(
    const float* __restrict__ x, const float* __restrict__ g,
    const float* __restrict__ b, u16* __restrict__ out)
{
    int r = blockIdx.x; int t = threadIdx.x;
    size_t i = (size_t)r*DD + t;
    float v = x[i];
    float s = v, ss = v*v;
    #pragma unroll
    for (int o=32;o>=1;o>>=1){ s += __shfl_xor(s,o); ss += __shfl_xor(ss,o); }
    __shared__ float sh[8];
    int wave = t>>6, lane = t&63;
    if (lane==0){ sh[wave]=s; sh[4+wave]=ss; }
    __syncthreads();
    float S  = sh[0]+sh[1]+sh[2]+sh[3];
    float SS = sh[4]+sh[5]+sh[6]+sh[7];
    float mu  = S*(1.f/DD);
    float var = SS*(1.f/DD) - mu*mu;
    float inv = rsqrtf(var + 1e-5f);
    out[i] = f2bf((v-mu)*inv*g[t] + b[t]);
}

// ---------------- MFMA bf16 GEMM: C = act([A0|A1]@WT^T + bias) ---------------
// BM=64, BN=128, BK=64; 256 threads = 4 waves (2x2), wave tile 32x64.
// Frag-ordered LDS: [16-row block][k-octet][16 rows x 8 elems] — lane-linear.
template<int ACT, bool FINAL, typename CT>
__global__ __launch_bounds__(256) void mgemm(
    const u16* __restrict__ A0, const u16* __restrict__ A1, int kswitch, int lda,
    const u16* __restrict__ WT, int Kd,
    const float* __restrict__ bias, int actcol,
    CT* __restrict__ C, int ldc,
    const u16* __restrict__ addsrc, const int* __restrict__ rowmask)
{
    __shared__ u16 ldsA[4096];   // 64 rows x 64 k
    __shared__ u16 ldsB[8192];   // 128 cols x 64 k
    int t = threadIdx.x;
    int row0 = blockIdx.x*64, col0 = blockIdx.y*128;
    int l = t & 63, w = t >> 6;
    int wm = w >> 1, wn = w & 1;

    int s_ar = t >> 2, s_ao = t & 3;
    int aidx1 = (s_ar>>4)*1024 + s_ao*128 + (s_ar&15)*8;
    int aidx2 = aidx1 + 4*128;
    int s_bc = t >> 1, s_bo = (t & 1)*4;
    int bbase = (s_bc>>4)*1024 + (s_bc&15)*8;

    f32x4 acc[2][4];
    #pragma unroll
    for (int mf=0;mf<2;++mf)
        #pragma unroll
        for (int nf=0;nf<4;++nf)
            acc[mf][nf] = (f32x4){0.f,0.f,0.f,0.f};

    uint4 av1, av2, bv0, bv1, bv2, bv3;
    {
        const u16* Ab = A0; int kk = 0;
        const u16* ap = Ab + (size_t)(row0+s_ar)*lda + kk;
        av1 = *(const uint4*)(ap + s_ao*8);
        av2 = *(const uint4*)(ap + 32 + s_ao*8);
        const u16* bp = WT + (size_t)(col0 + s_bc)*Kd + s_bo*8;
        bv0 = *(const uint4*)(bp); bv1 = *(const uint4*)(bp+8);
        bv2 = *(const uint4*)(bp+16); bv3 = *(const uint4*)(bp+24);
    }

    for (int k0 = 0; k0 < Kd; k0 += 64){
        __syncthreads();
        *(uint4*)&ldsA[aidx1] = av1;
        *(uint4*)&ldsA[aidx2] = av2;
        *(uint4*)&ldsB[bbase + (s_bo  )*128] = bv0;
        *(uint4*)&ldsB[bbase + (s_bo+1)*128] = bv1;
        *(uint4*)&ldsB[bbase + (s_bo+2)*128] = bv2;
        *(uint4*)&ldsB[bbase + (s_bo+3)*128] = bv3;
        __syncthreads();
        int kn = k0 + 64;
        if (kn < Kd){
            const u16* Ab = A0; int kk = kn;
            if (kn >= kswitch){ Ab = A1; kk = kn - kswitch; }
            const u16* ap = Ab + (size_t)(row0+s_ar)*lda + kk;
            av1 = *(const uint4*)(ap + s_ao*8);
            av2 = *(const uint4*)(ap + 32 + s_ao*8);
            const u16* bp = WT + (size_t)(col0 + s_bc)*Kd + kn + s_bo*8;
            bv0 = *(const uint4*)(bp); bv1 = *(const uint4*)(bp+8);
            bv2 = *(const uint4*)(bp+16); bv3 = *(const uint4*)(bp+24);
        }
        #pragma unroll
        for (int s=0;s<2;++s){
            s16x8 af[2], bfr[4];
            #pragma unroll
            for (int mf=0;mf<2;++mf) af[mf] = *(s16x8*)&ldsA[(wm*2+mf)*1024 + (s*4+(l>>4))*128 + (l&15)*8];
            #pragma unroll
            for (int nf=0;nf<4;++nf) bfr[nf] = *(s16x8*)&ldsB[(wn*4+nf)*1024 + (s*4+(l>>4))*128 + (l&15)*8];
            #pragma unroll
            for (int mf=0; mf<2; ++mf)
                #pragma unroll
                for (int nf=0; nf<4; ++nf)
                    acc[mf][nf] = __builtin_amdgcn_mfma_f32_16x16x32_bf16(af[mf], bfr[nf], acc[mf][nf], 0,0,0);
        }
    }

    int lrow = (l>>4)*4, lcol = l&15;
    #pragma unroll
    for (int mf=0; mf<2; ++mf){
        #pragma unroll
        for (int nf=0; nf<4; ++nf){
            int col = col0 + wn*64 + nf*16 + lcol;
            float bv = bias ? bias[col] : 0.f;
            #pragma unroll
            for (int i=0;i<4;++i){
                int row = row0 + wm*32 + mf*16 + lrow + i;
                float v = acc[mf][nf][i] + bv;
                if (ACT==1){ if (col >= actcol) v = gelu_f(v); }
                else if (ACT==2) v = 1.f/(1.f+expf(-v));
                if (FINAL){
                    float mfv = (float)rowmask[row];
                    v = (bf2f(addsrc[(size_t)row*ldc + col]) + v) * mfv;
                }
                if constexpr (sizeof(CT)==2) C[(size_t)row*ldc+col] = (CT)f2bf(v);
                else                         C[(size_t)row*ldc+col] = v;
            }
        }
    }
}

// ------------- rel-pos bias table --------------------------------------------
__global__ __launch_bounds__(256) void bias_tab_kernel(
    const float* __restrict__ emb, const float* __restrict__ we1,
    const float* __restrict__ be1, const float* __restrict__ we2,
    const float* __restrict__ be2, float* __restrict__ tab)
{
    int r = blockIdx.x; int j = threadIdx.x;
    float acc = be1[j];
    #pragma unroll 8
    for (int d=0; d<64; ++d) acc += emb[r*64+d]*we1[d*256+j];
    float tv = gelu_f(acc)*we2[j];
    #pragma unroll
    for (int o=32;o>=1;o>>=1) tv += __shfl_xor(tv,o);
    __shared__ float sh[4];
    int wave = j>>6, lane = j&63;
    if (lane==0) sh[wave]=tv;
    __syncthreads();
    if (j==0) tab[r] = sh[0]+sh[1]+sh[2]+sh[3] + be2[0];
}

// ------------- neighbor attention --------------------------------------------
// fold-reduce: 10 shuffles for 8 neighbor dots; V prefetched into regs.
__global__ __launch_bounds__(256) void nattn_kernel(
    const u16* __restrict__ nb,
    const int* __restrict__ nbr_idx, const int* __restrict__ nbr_mask,
    const int* __restrict__ rel_pos, const int* __restrict__ mask,
    const float* __restrict__ btab, u16* __restrict__ agg)
{
    int r = blockIdx.x;
    int b = r >> 11;
    int t = threadIdx.x, lane = t&63, wave = t>>6;
    __shared__ float s_w[32];
    __shared__ float s_agg[4][256];
    uint2 qu = *(const uint2*)&nb[(size_t)r*LDBIG + lane*4];
    float q0 = bf2f(qu.x&0xffff), q1 = bf2f(qu.x>>16);
    float q2 = bf2f(qu.y&0xffff), q3 = bf2f(qu.y>>16);
    int mrow = mask[r];

    uint2 kreg[8], vreg[8];
    #pragma unroll
    for (int j=0;j<8;++j){
        int idx = nbr_idx[r*32 + wave*8 + j];
        size_t grow = ((size_t)(b<<11) + idx)*LDBIG;
        kreg[j] = *(const uint2*)&nb[grow + 256 + lane*4];
        vreg[j] = *(const uint2*)&nb[grow + 512 + lane*4];
    }
    float d[8];
    #pragma unroll
    for (int j=0;j<8;++j){
        d[j] = q0*bf2f(kreg[j].x&0xffff) + q1*bf2f(kreg[j].x>>16)
             + q2*bf2f(kreg[j].y&0xffff) + q3*bf2f(kreg[j].y>>16);
    }
    // fold-reduce: result on lane l is full sum for neighbor (l&7)
    #define CMB(a,b,s) ({ float _t = (lane&(s)) ? (a) : (b); float _r = __shfl_xor(_t,(s)); (lane&(s)) ? ((b)+_r) : ((a)+_r); })
    float e10 = CMB(d[0],d[1],1), e11 = CMB(d[2],d[3],1);
    float e12 = CMB(d[4],d[5],1), e13 = CMB(d[6],d[7],1);
    float e20 = CMB(e10,e11,2),   e21 = CMB(e12,e13,2);
    float e3  = CMB(e20,e21,4);
    #undef CMB
    e3 += __shfl_xor(e3,8); e3 += __shfl_xor(e3,16); e3 += __shfl_xor(e3,32);
    if (lane < 8){
        int k = wave*8 + lane;
        int rp = rel_pos[r*32+k];
        rp = rp < -32 ? -32 : (rp > 32 ? 32 : rp);
        float logit = e3*0.0625f + btab[rp+32];
        int am = nbr_mask[r*32+k] * mrow;
        s_w[k] = am ? logit : -3.402823466e38f;
    }
    __syncthreads();
    if (wave==0){
        float lg = (lane<32) ? s_w[lane] : -3.402823466e38f;
        float m = lg;
        #pragma unroll
        for (int o=16;o>=1;o>>=1) m = fmaxf(m, __shfl_xor(m,o));
        float e = (lane<32) ? expf(lg-m) : 0.f;
        float ssum = e;
        #pragma unroll
        for (int o=16;o>=1;o>>=1) ssum += __shfl_xor(ssum,o);
        if (lane<32) s_w[lane] = e/ssum;
    }
    __syncthreads();
    float4 av = {0.f,0.f,0.f,0.f};
    #pragma unroll
    for (int j=0;j<8;++j){
        float wk = s_w[wave*8 + j];
        av.x += wk*bf2f(vreg[j].x&0xffff); av.y += wk*bf2f(vreg[j].x>>16);
        av.z += wk*bf2f(vreg[j].y&0xffff); av.w += wk*bf2f(vreg[j].y>>16);
    }
    *(float4*)&s_agg[wave][lane*4] = av;
    __syncthreads();
    float sum = s_agg[0][t]+s_agg[1][t]+s_agg[2][t]+s_agg[3][t];
    agg[(size_t)r*256 + t] = f2bf(sum);
}

// ------------- linear-attn stats (phi on k only; v just masked) --------------
__global__ __launch_bounds__(256) void linstats_kernel(
    const u16* __restrict__ qkv, const int* __restrict__ mask,
    float* __restrict__ kv, float* __restrict__ ksum)
{
    int blk = blockIdx.x;
    int bh = blk >> 4, ch = blk & 15;
    int b = bh >> 3, hh = bh & 7;
    int t = threadIdx.x;
    int d = t >> 3, m4 = (t & 7)*4;
    __shared__ float sk[8][32], sv[8][32];
    float a0=0,a1=0,a2=0,a3=0, aks=0;
    int l0 = ch*128;
    int half = t >> 7, tt = t & 127;
    int lr = tt >> 4, e2 = (tt & 15)*2;
    for (int g8=0; g8<16; ++g8){
        int l = l0 + g8*8 + lr;
        size_t base = ((size_t)b*LSEQ + l)*LDBIG + (half ? 1280 : 1024) + hh*32 + e2;
        u32 u = *(const u32*)&qkv[base];
        float mf = (float)mask[b*LSEQ + l];
        float x0 = bf2f((u16)(u & 0xffff));
        float x1 = bf2f((u16)(u >> 16));
        if (half==0){ sk[lr][e2] = phi_f(x0)*mf; sk[lr][e2+1] = phi_f(x1)*mf; }
        else        { sv[lr][e2] = x0*mf;        sv[lr][e2+1] = x1*mf; }
        __syncthreads();
        #pragma unroll
        for (int rr=0;rr<8;++rr){
            float kd = sk[rr][d];
            a0 += kd*sv[rr][m4]; a1 += kd*sv[rr][m4+1];
            a2 += kd*sv[rr][m4+2]; a3 += kd*sv[rr][m4+3];
            if ((t&7)==0) aks += kd;
        }
        __syncthreads();
    }
    size_t kb = (size_t)bh*1024 + d*32 + m4;
    atomicAdd(&kv[kb+0],a0); atomicAdd(&kv[kb+1],a1);
    atomicAdd(&kv[kb+2],a2); atomicAdd(&kv[kb+3],a3);
    if ((t&7)==0) atomicAdd(&ksum[bh*32+d], aks);
}

// ------------- linear-attn apply ---------------------------------------------
__global__ __launch_bounds__(256) void linapply_kernel(
    const u16* __restrict__ qkv, const float* __restrict__ kv,
    const float* __restrict__ ksum, u16* __restrict__ y)
{
    int r = blockIdx.x; int b = r >> 11;
    int t = threadIdx.x;
    __shared__ float sq[256];
    if (t < 128){
        u32 u = *(const u32*)&qkv[(size_t)r*LDBIG + 768 + t*2];
        sq[t*2]   = phi_f(bf2f((u16)(u & 0xffff)));
        sq[t*2+1] = phi_f(bf2f((u16)(u >> 16)));
    }
    __syncthreads();
    int hh = t>>5, m = t&31;
    const float* kvb = &kv[(size_t)((b<<3)+hh)*1024 + m];
    const float* ksb = &ksum[((b<<3)+hh)*32];
    const float* sqh = &sq[hh*32];
    float acc=0.f, az=0.f;
    #pragma unroll
    for (int dd=0; dd<32; ++dd){
        float qd = sqh[dd];
        acc += qd * kvb[dd*32];
        az  += qd * ksb[dd];
    }
    y[(size_t)r*256 + t] = f2bf(acc / (az + 1e-6f));
}

// ------------- fw = softmax2(f1 @ wf2 + bf2) ---------------------------------
__global__ __launch_bounds__(64) void fw_kernel(
    const u16* __restrict__ f1, const float* __restrict__ wf2,
    const float* __restrict__ bf2, float* __restrict__ fw)
{
    int r = blockIdx.x; int lane = threadIdx.x;
    uint2 fu = *(const uint2*)&f1[(size_t)r*LDBIG + 1536 + lane*4];
    float v0 = bf2f(fu.x&0xffff), v1 = bf2f(fu.x>>16);
    float v2 = bf2f(fu.y&0xffff), v3 = bf2f(fu.y>>16);
    int dd = lane*4;
    float p0 = v0*wf2[dd*2]   + v1*wf2[dd*2+2] + v2*wf2[dd*2+4] + v3*wf2[dd*2+6];
    float p1 = v0*wf2[dd*2+1] + v1*wf2[dd*2+3] + v2*wf2[dd*2+5] + v3*wf2[dd*2+7];
    #pragma unroll
    for (int o=32;o>=1;o>>=1){ p0 += __shfl_xor(p0,o); p1 += __shfl_xor(p1,o); }
    if (lane==0){
        float a0=p0+bf2[0], a1=p1+bf2[1];
        float mx = fmaxf(a0,a1);
        float e0=expf(a0-mx), e1=expf(a1-mx);
        float s = e0+e1;
        fw[r*2] = e0/s; fw[r*2+1] = e1/s;
    }
}

// ------------- combine: x2 = fw0*h_local + fw1*h_global; hn = LN(x2) ---------
__global__ __launch_bounds__(128) void combine_kernel(
    const u16* __restrict__ h, const u16* __restrict__ agglo,
    const u16* __restrict__ g, const u16* __restrict__ ygo,
    const float* __restrict__ fw, const int* __restrict__ mask,
    const float* __restrict__ g2, const float* __restrict__ b2,
    u16* __restrict__ x2, u16* __restrict__ hn)
{
    int r = blockIdx.x, t = threadIdx.x;
    size_t i = (size_t)r*DD + t*2;
    float mf = (float)mask[r];
    u32 hu = *(const u32*)&h[i],  au = *(const u32*)&agglo[i];
    u32 gu = *(const u32*)&g[i],  yu = *(const u32*)&ygo[i];
    float f0 = fw[r*2], f1v = fw[r*2+1];
    float hv0 = bf2f((u16)(hu&0xffff)), hv1 = bf2f((u16)(hu>>16));
    float ag0 = bf2f((u16)(au&0xffff)), ag1 = bf2f((u16)(au>>16));
    float gg0 = bf2f((u16)(gu&0xffff)), gg1 = bf2f((u16)(gu>>16));
    float yy0 = bf2f((u16)(yu&0xffff)), yy1 = bf2f((u16)(yu>>16));
    float v0 = f0*((hv0 + gg0*ag0)*mf) + f1v*(hv0 + yy0*mf);
    float v1 = f0*((hv1 + gg1*ag1)*mf) + f1v*(hv1 + yy1*mf);
    *(u32*)&x2[i] = (u32)f2bf(v0) | ((u32)f2bf(v1)<<16);
    float s = v0+v1, ss = v0*v0+v1*v1;
    #pragma unroll
    for (int o=32;o>=1;o>>=1){ s += __shfl_xor(s,o); ss += __shfl_xor(ss,o); }
    __shared__ float sh[4];
    int wave = t>>6, lane = t&63;
    if (lane==0){ sh[wave]=s; sh[2+wave]=ss; }
    __syncthreads();
    float S  = sh[0]+sh[1];
    float SS = sh[2]+sh[3];
    float mu  = S*(1.f/DD);
    float var = SS*(1.f/DD) - mu*mu;
    float inv = rsqrtf(var + 1e-5f);
    int j0 = t*2;
    float o0 = (v0-mu)*inv*g2[j0]   + b2[j0];
    float o1 = (v1-mu)*inv*g2[j0+1] + b2[j0+1];
    *(u32*)&hn[i] = (u32)f2bf(o0) | ((u32)f2bf(o1)<<16);
}

// =============================================================================
extern "C" void kernel_launch(void* const* d_in, const int* in_sizes, int n_in,
                              void* d_out, int out_size, void* d_ws, size_t ws_size,
                              hipStream_t stream)
{
    const float* x        = (const float*)d_in[0];
    const int*   mask     = (const int*)  d_in[1];
    const int*   nbr_idx  = (const int*)  d_in[2];
    const int*   nbr_mask = (const int*)  d_in[3];
    const int*   rel_pos  = (const int*)  d_in[4];
    const float* g1   = (const float*)d_in[5];
    const float* b1   = (const float*)d_in[6];
    const float* wq   = (const float*)d_in[7];
    const float* wk   = (const float*)d_in[8];
    const float* wv   = (const float*)d_in[9];
    const float* relpos_emb = (const float*)d_in[10];
    const float* we1  = (const float*)d_in[11];
    const float* be1  = (const float*)d_in[12];
    const float* we2  = (const float*)d_in[13];
    const float* be2  = (const float*)d_in[14];
    const float* wg1  = (const float*)d_in[15];
    const float* bg1  = (const float*)d_in[16];
    const float* wg2  = (const float*)d_in[17];
    const float* bg2  = (const float*)d_in[18];
    const float* wlo  = (const float*)d_in[19];
    const float* blo  = (const float*)d_in[20];
    const float* wqkv = (const float*)d_in[21];
    const float* wgo  = (const float*)d_in[22];
    const float* wf1  = (const float*)d_in[23];
    const float* bf1  = (const float*)d_in[24];
    const float* wf2  = (const float*)d_in[25];
    const float* bf2  = (const float*)d_in[26];
    const float* g2   = (const float*)d_in[27];
    const float* b2   = (const float*)d_in[28];
    const float* wff1 = (const float*)d_in[29];
    const float* bff1 = (const float*)d_in[30];
    const float* wff2 = (const float*)d_in[31];
    const float* bff2 = (const float*)d_in[32];
    float* out = (float*)d_out;

    unsigned char* wsb = (unsigned char*)d_ws;
    u16* bigout  = (u16*)(wsb + ((size_t)0<<20));   // 8192x1792 bf16 = 29.4MB; reused for ffn1
    u16* h_bf    = (u16*)(wsb + ((size_t)30<<20));
    u16* agg_bf  = (u16*)(wsb + ((size_t)34<<20));  // later g
    u16* agglo_bf= (u16*)(wsb + ((size_t)38<<20));
    u16* x2y_bf  = (u16*)(wsb + ((size_t)42<<20));  // y, then x2
    u16* tg_bf   = (u16*)(wsb + ((size_t)46<<20));
    u16* ygo_bf  = (u16*)(wsb + ((size_t)50<<20));
    u16* hn_bf   = (u16*)(wsb + ((size_t)54<<20));
    u16* WT      = (u16*)(wsb + ((size_t)58<<20));  // 2.62MB
    float* btab  = (float*)(wsb + ((size_t)61<<20)); // 65
    float* bbig  = btab + 128;                       // 1792
    float* kvb   = bbig + 2048;                      // 32768
    float* ksb   = kvb + 32768;                      // 1024
    float* fwb   = ksb + 1024;                       // 16384

    // WT sub-offsets (u16 units)
    const int WT_BIG  = 0;        // [1792][256]: q|k|v|qkv|f1
    const int WT_LO   = 458752;   // [256][256]
    const int WT_G1   = 524288;   // [256][512]
    const int WT_G2   = 655360;   // [256][256]
    const int WT_GO   = 720896;   // [256][256]
    const int WT_FF1  = 786432;   // [1024][256]
    const int WT_FF2  = 1048576;  // [256][1024]

    TransArgs ta;
    ta.d[0]  = { wq,   WT_BIG + 0,        256,  256,    0 };
    ta.d[1]  = { wk,   WT_BIG + 65536,    256,  256,   64 };
    ta.d[2]  = { wv,   WT_BIG + 131072,   256,  256,  128 };
    ta.d[3]  = { wqkv, WT_BIG + 196608,   256,  768,  192 };
    ta.d[4]  = { wf1,  WT_BIG + 393216,   256,  256,  384 };
    ta.d[5]  = { wlo,  WT_LO,             256,  256,  448 };
    ta.d[6]  = { wg1,  WT_G1,             512,  256,  512 };
    ta.d[7]  = { wg2,  WT_G2,             256,  256,  640 };
    ta.d[8]  = { wgo,  WT_GO,             256,  256,  704 };
    ta.d[9]  = { wff1, WT_FF1,            256, 1024,  768 };
    ta.d[10] = { wff2, WT_FF2,           1024,  256, 1024 };
    // total tiles: 1280

    const int KBIG = 1<<30;
    dim3 blk(256);

    transpose_kernel<<<1280, blk, 0, stream>>>(ta, WT);
    biasbig_kernel<<<7, blk, 0, stream>>>(bf1, bbig);
    ln_kernel<<<NROWS, blk, 0, stream>>>(x, g1, b1, h_bf);
    bias_tab_kernel<<<65, blk, 0, stream>>>(relpos_emb, we1, be1, we2, be2, btab);
    hipMemsetAsync(kvb, 0, (32768+1024)*sizeof(float), stream);
    // big: [nb(q|k|v) | qkv(qg|kg|vg) | gelu(f1)] = h @ WT_BIG
    mgemm<1,false,u16><<<dim3(128,14), blk, 0, stream>>>(h_bf, h_bf, KBIG, 256, WT+WT_BIG, 256, bbig, 1536, bigout, LDBIG, nullptr, nullptr);
    fw_kernel<<<NROWS, dim3(64), 0, stream>>>(bigout, wf2, bf2, fwb);
    linstats_kernel<<<512, blk, 0, stream>>>(bigout, mask, kvb, ksb);
    linapply_kernel<<<NROWS, blk, 0, stream>>>(bigout, kvb, ksb, x2y_bf);   // y
    mgemm<0,false,u16><<<dim3(128,2), blk, 0, stream>>>(x2y_bf, x2y_bf, KBIG, 256, WT+WT_GO, 256, nullptr, 0, ygo_bf, 256, nullptr, nullptr);
    nattn_kernel<<<NROWS, blk, 0, stream>>>(bigout, nbr_idx, nbr_mask, rel_pos, mask, btab, agg_bf);
    mgemm<0,false,u16><<<dim3(128,2), blk, 0, stream>>>(agg_bf, agg_bf, KBIG, 256, WT+WT_LO, 256, blo, 0, agglo_bf, 256, nullptr, nullptr);
    mgemm<1,false,u16><<<dim3(128,2), blk, 0, stream>>>(h_bf, agglo_bf, 256, 256, WT+WT_G1, 512, bg1, 0, tg_bf, 256, nullptr, nullptr);
    mgemm<2,false,u16><<<dim3(128,2), blk, 0, stream>>>(tg_bf, tg_bf, KBIG, 256, WT+WT_G2, 256, bg2, 0, agg_bf, 256, nullptr, nullptr); // g -> agg slot
    combine_kernel<<<NROWS, dim3(128), 0, stream>>>(h_bf, agglo_bf, agg_bf, ygo_bf, fwb, mask, g2, b2, x2y_bf, hn_bf);
    mgemm<1,false,u16><<<dim3(128,8), blk, 0, stream>>>(hn_bf, hn_bf, KBIG, 256, WT+WT_FF1, 256, bff1, 0, bigout, 1024, nullptr, nullptr); // ffn1
    mgemm<0,true,float><<<dim3(128,2), blk, 0, stream>>>(bigout, bigout, KBIG, 1024, WT+WT_FF2, 1024, bff2, 0, out, 256, x2y_bf, mask);
}

// Round 6
// 277.615 us; speedup vs baseline: 2.8291x; 1.0685x over previous
//
#include <hip/hip_runtime.h>
#include <math.h>

#define LSEQ 2048
#define BB 4
#define DD 256
#define NROWS (BB*LSEQ)   // 8192
#define LDBIG 1792

typedef unsigned short u16;
typedef unsigned int u32;
typedef short s16x8 __attribute__((ext_vector_type(8)));
typedef float f32x4 __attribute__((ext_vector_type(4)));

__device__ __forceinline__ float gelu_f(float x){
    return 0.5f*x*(1.0f+erff(x*0.70710678118654752440f));
}
__device__ __forceinline__ float phi_f(float z){ return z>0.f ? z+1.f : expf(z); }
__device__ __forceinline__ float bf2f(u16 u){ union{u32 i; float f;} x; x.i = ((u32)u)<<16; return x.f; }
__device__ __forceinline__ u16 f2bf(float f){ union{float f; u32 i;} x; x.f = f; u32 r = (x.i + 0x7fff + ((x.i>>16)&1)) >> 16; return (u16)r; }

// ---------------- prep: transpose | LN | bias-table | kv-zero ----------------
// blockIdx ranges: [0,1280) transpose, [1280,9472) LN, [9472,9537) btab,
// [9537,9669) kv zero.
struct TransDesc { const float* src; int dstoff; int K; int N; int tstart; };
struct TransArgs { TransDesc d[11]; };

__global__ __launch_bounds__(256) void prep_kernel(
    TransArgs args, u16* __restrict__ WT,
    const float* __restrict__ x, const float* __restrict__ g1,
    const float* __restrict__ b1, u16* __restrict__ h,
    const float* __restrict__ emb, const float* __restrict__ we1,
    const float* __restrict__ be1, const float* __restrict__ we2,
    const float* __restrict__ be2, float* __restrict__ btab,
    float* __restrict__ kvz)
{
    int bid = blockIdx.x;
    if (bid < 1280){
        // ---- weight transpose+cvt: WT[n][k] = bf16(W[k][n]) ----
        int z = 0;
        #pragma unroll
        for (int i=1;i<11;++i) if (bid >= args.d[i].tstart) z = i;
        TransDesc e = args.d[z];
        int tid = bid - e.tstart;
        int ntx = e.N >> 5;
        int kt = tid / ntx, nt = tid - kt*ntx;
        __shared__ float tile[32][33];
        int tx = threadIdx.x & 31, ty = threadIdx.x >> 5;
        #pragma unroll
        for (int i=0;i<4;++i){
            int k = kt*32 + ty + i*8;
            tile[ty+i*8][tx] = e.src[(size_t)k*e.N + nt*32 + tx];
        }
        __syncthreads();
        #pragma unroll
        for (int i=0;i<4;++i){
            int n = nt*32 + ty + i*8;
            WT[e.dstoff + (size_t)n*e.K + kt*32 + tx] = f2bf(tile[tx][ty+i*8]);
        }
    } else if (bid < 9472){
        // ---- LayerNorm row ----
        int r = bid - 1280; int t = threadIdx.x;
        size_t i = (size_t)r*DD + t;
        float v = x[i];
        float s = v, ss = v*v;
        #pragma unroll
        for (int o=32;o>=1;o>>=1){ s += __shfl_xor(s,o); ss += __shfl_xor(ss,o); }
        __shared__ float sh[8];
        int wave = t>>6, lane = t&63;
        if (lane==0){ sh[wave]=s; sh[4+wave]=ss; }
        __syncthreads();
        float S  = sh[0]+sh[1]+sh[2]+sh[3];
        float SS = sh[4]+sh[5]+sh[6]+sh[7];
        float mu  = S*(1.f/DD);
        float var = SS*(1.f/DD) - mu*mu;
        float inv = rsqrtf(var + 1e-5f);
        h[i] = f2bf((v-mu)*inv*g1[t] + b1[t]);
    } else if (bid < 9537){
        // ---- rel-pos bias table entry ----
        int r = bid - 9472; int j = threadIdx.x;
        float acc = be1[j];
        #pragma unroll 8
        for (int d=0; d<64; ++d) acc += emb[r*64+d]*we1[d*256+j];
        float tv = gelu_f(acc)*we2[j];
        #pragma unroll
        for (int o=32;o>=1;o>>=1) tv += __shfl_xor(tv,o);
        __shared__ float sh2[4];
        int wave = j>>6, lane = j&63;
        if (lane==0) sh2[wave]=tv;
        __syncthreads();
        if (j==0) btab[r] = sh2[0]+sh2[1]+sh2[2]+sh2[3] + be2[0];
    } else {
        // ---- zero kv/ksum accumulators (33792 floats) ----
        int idx = (bid - 9537)*256 + threadIdx.x;
        kvz[idx] = 0.f;
    }
}

// ---------------- MFMA bf16 GEMM core ----------------------------------------
// BM=64, BN=128, BK=64; 256 threads = 4 waves (2x2), wave tile 32x64.
// C = act([A0|A1] @ WT^T + bias). ACT==1: cols<actcol get no bias/no gelu,
// cols>=actcol get bias[col-actcol]+gelu.
template<int ACT, bool FINAL, typename CT>
__device__ __forceinline__ void mgemm_core(
    const u16* __restrict__ A0, const u16* __restrict__ A1, int kswitch, int lda,
    const u16* __restrict__ WT, int Kd,
    const float* __restrict__ bias, int actcol,
    CT* __restrict__ C, int ldc,
    const u16* __restrict__ addsrc, const int* __restrict__ rowmask,
    int row0, int col0)
{
    __shared__ u16 ldsA[4096];   // 64 rows x 64 k
    __shared__ u16 ldsB[8192];   // 128 cols x 64 k
    int t = threadIdx.x;
    int l = t & 63, w = t >> 6;
    int wm = w >> 1, wn = w & 1;

    int s_ar = t >> 2, s_ao = t & 3;
    int aidx1 = (s_ar>>4)*1024 + s_ao*128 + (s_ar&15)*8;
    int aidx2 = aidx1 + 4*128;
    int s_bc = t >> 1, s_bo = (t & 1)*4;
    int bbase = (s_bc>>4)*1024 + (s_bc&15)*8;

    f32x4 acc[2][4];
    #pragma unroll
    for (int mf=0;mf<2;++mf)
        #pragma unroll
        for (int nf=0;nf<4;++nf)
            acc[mf][nf] = (f32x4){0.f,0.f,0.f,0.f};

    uint4 av1, av2, bv0, bv1, bv2, bv3;
    {
        const u16* ap = A0 + (size_t)(row0+s_ar)*lda;
        av1 = *(const uint4*)(ap + s_ao*8);
        av2 = *(const uint4*)(ap + 32 + s_ao*8);
        const u16* bp = WT + (size_t)(col0 + s_bc)*Kd + s_bo*8;
        bv0 = *(const uint4*)(bp); bv1 = *(const uint4*)(bp+8);
        bv2 = *(const uint4*)(bp+16); bv3 = *(const uint4*)(bp+24);
    }

    for (int k0 = 0; k0 < Kd; k0 += 64){
        __syncthreads();
        *(uint4*)&ldsA[aidx1] = av1;
        *(uint4*)&ldsA[aidx2] = av2;
        *(uint4*)&ldsB[bbase + (s_bo  )*128] = bv0;
        *(uint4*)&ldsB[bbase + (s_bo+1)*128] = bv1;
        *(uint4*)&ldsB[bbase + (s_bo+2)*128] = bv2;
        *(uint4*)&ldsB[bbase + (s_bo+3)*128] = bv3;
        __syncthreads();
        int kn = k0 + 64;
        if (kn < Kd){
            const u16* Ab = A0; int kk = kn;
            if (kn >= kswitch){ Ab = A1; kk = kn - kswitch; }
            const u16* ap = Ab + (size_t)(row0+s_ar)*lda + kk;
            av1 = *(const uint4*)(ap + s_ao*8);
            av2 = *(const uint4*)(ap + 32 + s_ao*8);
            const u16* bp = WT + (size_t)(col0 + s_bc)*Kd + kn + s_bo*8;
            bv0 = *(const uint4*)(bp); bv1 = *(const uint4*)(bp+8);
            bv2 = *(const uint4*)(bp+16); bv3 = *(const uint4*)(bp+24);
        }
        #pragma unroll
        for (int s=0;s<2;++s){
            s16x8 af[2], bfr[4];
            #pragma unroll
            for (int mf=0;mf<2;++mf) af[mf] = *(s16x8*)&ldsA[(wm*2+mf)*1024 + (s*4+(l>>4))*128 + (l&15)*8];
            #pragma unroll
            for (int nf=0;nf<4;++nf) bfr[nf] = *(s16x8*)&ldsB[(wn*4+nf)*1024 + (s*4+(l>>4))*128 + (l&15)*8];
            #pragma unroll
            for (int mf=0; mf<2; ++mf)
                #pragma unroll
                for (int nf=0; nf<4; ++nf)
                    acc[mf][nf] = __builtin_amdgcn_mfma_f32_16x16x32_bf16(af[mf], bfr[nf], acc[mf][nf], 0,0,0);
        }
    }

    int lrow = (l>>4)*4, lcol = l&15;
    #pragma unroll
    for (int mf=0; mf<2; ++mf){
        #pragma unroll
        for (int nf=0; nf<4; ++nf){
            int col = col0 + wn*64 + nf*16 + lcol;
            float bv;
            if (ACT==1) bv = (col >= actcol) ? bias[col-actcol] : 0.f;
            else        bv = bias ? bias[col] : 0.f;
            #pragma unroll
            for (int i=0;i<4;++i){
                int row = row0 + wm*32 + mf*16 + lrow + i;
                float v = acc[mf][nf][i] + bv;
                if (ACT==1){ if (col >= actcol) v = gelu_f(v); }
                else if (ACT==2) v = 1.f/(1.f+expf(-v));
                if (FINAL){
                    float mfv = (float)rowmask[row];
                    v = (bf2f(addsrc[(size_t)row*ldc + col]) + v) * mfv;
                }
                if constexpr (sizeof(CT)==2) C[(size_t)row*ldc+col] = (CT)f2bf(v);
                else                         C[(size_t)row*ldc+col] = v;
            }
        }
    }
}

template<int ACT, bool FINAL, typename CT>
__global__ __launch_bounds__(256) void mgemm(
    const u16* __restrict__ A0, const u16* __restrict__ A1, int kswitch, int lda,
    const u16* __restrict__ WT, int Kd,
    const float* __restrict__ bias, int actcol,
    CT* __restrict__ C, int ldc,
    const u16* __restrict__ addsrc, const int* __restrict__ rowmask)
{
    mgemm_core<ACT,FINAL,CT>(A0,A1,kswitch,lda,WT,Kd,bias,actcol,C,ldc,addsrc,rowmask,
                             blockIdx.x*64, blockIdx.y*128);
}

// dual independent N=256,K=256 GEMMs in one dispatch (z selects config)
struct DualCfg { const u16* A; const u16* WT; const float* bias; u16* C; };
__global__ __launch_bounds__(256) void mgemm_dual(DualCfg c0, DualCfg c1)
{
    DualCfg c = blockIdx.z ? c1 : c0;
    mgemm_core<0,false,u16>(c.A, c.A, 1<<30, 256, c.WT, 256, c.bias, 0, c.C, 256,
                            nullptr, nullptr, blockIdx.x*64, blockIdx.y*128);
}

// ------------- neighbor attention --------------------------------------------
// fold-reduce: 10 shuffles for 8 neighbor dots; V prefetched into regs.
__global__ __launch_bounds__(256) void nattn_kernel(
    const u16* __restrict__ nb,
    const int* __restrict__ nbr_idx, const int* __restrict__ nbr_mask,
    const int* __restrict__ rel_pos, const int* __restrict__ mask,
    const float* __restrict__ btab, u16* __restrict__ agg)
{
    int r = blockIdx.x;
    int b = r >> 11;
    int t = threadIdx.x, lane = t&63, wave = t>>6;
    __shared__ float s_w[32];
    __shared__ float s_agg[4][256];
    uint2 qu = *(const uint2*)&nb[(size_t)r*LDBIG + lane*4];
    float q0 = bf2f(qu.x&0xffff), q1 = bf2f(qu.x>>16);
    float q2 = bf2f(qu.y&0xffff), q3 = bf2f(qu.y>>16);
    int mrow = mask[r];

    uint2 kreg[8], vreg[8];
    #pragma unroll
    for (int j=0;j<8;++j){
        int idx = nbr_idx[r*32 + wave*8 + j];
        size_t grow = ((size_t)(b<<11) + idx)*LDBIG;
        kreg[j] = *(const uint2*)&nb[grow + 256 + lane*4];
        vreg[j] = *(const uint2*)&nb[grow + 512 + lane*4];
    }
    float d[8];
    #pragma unroll
    for (int j=0;j<8;++j){
        d[j] = q0*bf2f(kreg[j].x&0xffff) + q1*bf2f(kreg[j].x>>16)
             + q2*bf2f(kreg[j].y&0xffff) + q3*bf2f(kreg[j].y>>16);
    }
    // fold-reduce: result on lane l is full sum for neighbor (l&7)
    #define CMB(a,b,s) ({ float _t = (lane&(s)) ? (a) : (b); float _r = __shfl_xor(_t,(s)); (lane&(s)) ? ((b)+_r) : ((a)+_r); })
    float e10 = CMB(d[0],d[1],1), e11 = CMB(d[2],d[3],1);
    float e12 = CMB(d[4],d[5],1), e13 = CMB(d[6],d[7],1);
    float e20 = CMB(e10,e11,2),   e21 = CMB(e12,e13,2);
    float e3  = CMB(e20,e21,4);
    #undef CMB
    e3 += __shfl_xor(e3,8); e3 += __shfl_xor(e3,16); e3 += __shfl_xor(e3,32);
    if (lane < 8){
        int k = wave*8 + lane;
        int rp = rel_pos[r*32+k];
        rp = rp < -32 ? -32 : (rp > 32 ? 32 : rp);
        float logit = e3*0.0625f + btab[rp+32];
        int am = nbr_mask[r*32+k] * mrow;
        s_w[k] = am ? logit : -3.402823466e38f;
    }
    __syncthreads();
    if (wave==0){
        float lg = (lane<32) ? s_w[lane] : -3.402823466e38f;
        float m = lg;
        #pragma unroll
        for (int o=16;o>=1;o>>=1) m = fmaxf(m, __shfl_xor(m,o));
        float e = (lane<32) ? expf(lg-m) : 0.f;
        float ssum = e;
        #pragma unroll
        for (int o=16;o>=1;o>>=1) ssum += __shfl_xor(ssum,o);
        if (lane<32) s_w[lane] = e/ssum;
    }
    __syncthreads();
    float4 av = {0.f,0.f,0.f,0.f};
    #pragma unroll
    for (int j=0;j<8;++j){
        float wk = s_w[wave*8 + j];
        av.x += wk*bf2f(vreg[j].x&0xffff); av.y += wk*bf2f(vreg[j].x>>16);
        av.z += wk*bf2f(vreg[j].y&0xffff); av.w += wk*bf2f(vreg[j].y>>16);
    }
    *(float4*)&s_agg[wave][lane*4] = av;
    __syncthreads();
    float sum = s_agg[0][t]+s_agg[1][t]+s_agg[2][t]+s_agg[3][t];
    agg[(size_t)r*256 + t] = f2bf(sum);
}

// ------------- linear-attn stats (phi on k only; v just masked) --------------
__global__ __launch_bounds__(256) void linstats_kernel(
    const u16* __restrict__ qkv, const int* __restrict__ mask,
    float* __restrict__ kv, float* __restrict__ ksum)
{
    int blk = blockIdx.x;
    int bh = blk >> 4, ch = blk & 15;
    int b = bh >> 3, hh = bh & 7;
    int t = threadIdx.x;
    int d = t >> 3, m4 = (t & 7)*4;
    __shared__ float sk[8][32], sv[8][32];
    float a0=0,a1=0,a2=0,a3=0, aks=0;
    int l0 = ch*128;
    int half = t >> 7, tt = t & 127;
    int lr = tt >> 4, e2 = (tt & 15)*2;
    for (int g8=0; g8<16; ++g8){
        int l = l0 + g8*8 + lr;
        size_t base = ((size_t)b*LSEQ + l)*LDBIG + (half ? 1280 : 1024) + hh*32 + e2;
        u32 u = *(const u32*)&qkv[base];
        float mf = (float)mask[b*LSEQ + l];
        float x0 = bf2f((u16)(u & 0xffff));
        float x1 = bf2f((u16)(u >> 16));
        if (half==0){ sk[lr][e2] = phi_f(x0)*mf; sk[lr][e2+1] = phi_f(x1)*mf; }
        else        { sv[lr][e2] = x0*mf;        sv[lr][e2+1] = x1*mf; }
        __syncthreads();
        #pragma unroll
        for (int rr=0;rr<8;++rr){
            float kd = sk[rr][d];
            a0 += kd*sv[rr][m4]; a1 += kd*sv[rr][m4+1];
            a2 += kd*sv[rr][m4+2]; a3 += kd*sv[rr][m4+3];
            if ((t&7)==0) aks += kd;
        }
        __syncthreads();
    }
    size_t kb = (size_t)bh*1024 + d*32 + m4;
    atomicAdd(&kv[kb+0],a0); atomicAdd(&kv[kb+1],a1);
    atomicAdd(&kv[kb+2],a2); atomicAdd(&kv[kb+3],a3);
    if ((t&7)==0) atomicAdd(&ksum[bh*32+d], aks);
}

// ------------- linear-attn apply ---------------------------------------------
__global__ __launch_bounds__(256) void linapply_kernel(
    const u16* __restrict__ qkv, const float* __restrict__ kv,
    const float* __restrict__ ksum, u16* __restrict__ y)
{
    int r = blockIdx.x; int b = r >> 11;
    int t = threadIdx.x;
    __shared__ float sq[256];
    if (t < 128){
        u32 u = *(const u32*)&qkv[(size_t)r*LDBIG + 768 + t*2];
        sq[t*2]   = phi_f(bf2f((u16)(u & 0xffff)));
        sq[t*2+1] = phi_f(bf2f((u16)(u >> 16)));
    }
    __syncthreads();
    int hh = t>>5, m = t&31;
    const float* kvb = &kv[(size_t)((b<<3)+hh)*1024 + m];
    const float* ksb = &ksum[((b<<3)+hh)*32];
    const float* sqh = &sq[hh*32];
    float acc=0.f, az=0.f;
    #pragma unroll
    for (int dd=0; dd<32; ++dd){
        float qd = sqh[dd];
        acc += qd * kvb[dd*32];
        az  += qd * ksb[dd];
    }
    y[(size_t)r*256 + t] = f2bf(acc / (az + 1e-6f));
}

// ------------- combine (+inline fw softmax): x2, hn = LN(x2) -----------------
__global__ __launch_bounds__(128) void combine_kernel(
    const u16* __restrict__ h, const u16* __restrict__ agglo,
    const u16* __restrict__ g, const u16* __restrict__ ygo,
    const u16* __restrict__ bigout, const float* __restrict__ wf2,
    const float* __restrict__ bf2v, const int* __restrict__ mask,
    const float* __restrict__ g2, const float* __restrict__ b2,
    u16* __restrict__ x2, u16* __restrict__ hn)
{
    int r = blockIdx.x, t = threadIdx.x;
    int wave = t>>6, lane = t&63;
    // ---- fw = softmax2(f1 @ wf2 + bf2) ----
    u32 fu = *(const u32*)&bigout[(size_t)r*LDBIG + 1536 + t*2];
    float fa = bf2f((u16)(fu&0xffff)), fb = bf2f((u16)(fu>>16));
    int dd = t*2;
    float p0 = fa*wf2[dd*2]   + fb*wf2[dd*2+2];
    float p1 = fa*wf2[dd*2+1] + fb*wf2[dd*2+3];
    #pragma unroll
    for (int o=32;o>=1;o>>=1){ p0 += __shfl_xor(p0,o); p1 += __shfl_xor(p1,o); }
    __shared__ float shp[4];
    if (lane==0){ shp[wave]=p0; shp[2+wave]=p1; }
    __syncthreads();
    float P0 = shp[0]+shp[1]+bf2v[0], P1 = shp[2]+shp[3]+bf2v[1];
    float mx = fmaxf(P0,P1);
    float e0 = expf(P0-mx), e1 = expf(P1-mx);
    float f0 = e0/(e0+e1), f1v = e1/(e0+e1);
    // ---- mix + LN ----
    size_t i = (size_t)r*DD + t*2;
    float mf = (float)mask[r];
    u32 hu = *(const u32*)&h[i],  au = *(const u32*)&agglo[i];
    u32 gu = *(const u32*)&g[i],  yu = *(const u32*)&ygo[i];
    float hv0 = bf2f((u16)(hu&0xffff)), hv1 = bf2f((u16)(hu>>16));
    float ag0 = bf2f((u16)(au&0xffff)), ag1 = bf2f((u16)(au>>16));
    float gg0 = bf2f((u16)(gu&0xffff)), gg1 = bf2f((u16)(gu>>16));
    float yy0 = bf2f((u16)(yu&0xffff)), yy1 = bf2f((u16)(yu>>16));
    float v0 = f0*((hv0 + gg0*ag0)*mf) + f1v*(hv0 + yy0*mf);
    float v1 = f0*((hv1 + gg1*ag1)*mf) + f1v*(hv1 + yy1*mf);
    *(u32*)&x2[i] = (u32)f2bf(v0) | ((u32)f2bf(v1)<<16);
    float s = v0+v1, ss = v0*v0+v1*v1;
    #pragma unroll
    for (int o=32;o>=1;o>>=1){ s += __shfl_xor(s,o); ss += __shfl_xor(ss,o); }
    __shared__ float sh[4];
    if (lane==0){ sh[wave]=s; sh[2+wave]=ss; }
    __syncthreads();
    float S  = sh[0]+sh[1];
    float SS = sh[2]+sh[3];
    float mu  = S*(1.f/DD);
    float var = SS*(1.f/DD) - mu*mu;
    float inv = rsqrtf(var + 1e-5f);
    int j0 = t*2;
    float o0 = (v0-mu)*inv*g2[j0]   + b2[j0];
    float o1 = (v1-mu)*inv*g2[j0+1] + b2[j0+1];
    *(u32*)&hn[i] = (u32)f2bf(o0) | ((u32)f2bf(o1)<<16);
}

// =============================================================================
extern "C" void kernel_launch(void* const* d_in, const int* in_sizes, int n_in,
                              void* d_out, int out_size, void* d_ws, size_t ws_size,
                              hipStream_t stream)
{
    const float* x        = (const float*)d_in[0];
    const int*   mask     = (const int*)  d_in[1];
    const int*   nbr_idx  = (const int*)  d_in[2];
    const int*   nbr_mask = (const int*)  d_in[3];
    const int*   rel_pos  = (const int*)  d_in[4];
    const float* g1   = (const float*)d_in[5];
    const float* b1   = (const float*)d_in[6];
    const float* wq   = (const float*)d_in[7];
    const float* wk   = (const float*)d_in[8];
    const float* wv   = (const float*)d_in[9];
    const float* relpos_emb = (const float*)d_in[10];
    const float* we1  = (const float*)d_in[11];
    const float* be1  = (const float*)d_in[12];
    const float* we2  = (const float*)d_in[13];
    const float* be2  = (const float*)d_in[14];
    const float* wg1  = (const float*)d_in[15];
    const float* bg1  = (const float*)d_in[16];
    const float* wg2  = (const float*)d_in[17];
    const float* bg2  = (const float*)d_in[18];
    const float* wlo  = (const float*)d_in[19];
    const float* blo  = (const float*)d_in[20];
    const float* wqkv = (const float*)d_in[21];
    const float* wgo  = (const float*)d_in[22];
    const float* wf1  = (const float*)d_in[23];
    const float* bf1  = (const float*)d_in[24];
    const float* wf2  = (const float*)d_in[25];
    const float* bf2  = (const float*)d_in[26];
    const float* g2   = (const float*)d_in[27];
    const float* b2   = (const float*)d_in[28];
    const float* wff1 = (const float*)d_in[29];
    const float* bff1 = (const float*)d_in[30];
    const float* wff2 = (const float*)d_in[31];
    const float* bff2 = (const float*)d_in[32];
    float* out = (float*)d_out;

    unsigned char* wsb = (unsigned char*)d_ws;
    u16* bigout  = (u16*)(wsb + ((size_t)0<<20));   // 8192x1792 bf16 = 29.4MB; reused for ffn1
    u16* h_bf    = (u16*)(wsb + ((size_t)30<<20));
    u16* agg_bf  = (u16*)(wsb + ((size_t)34<<20));  // later g
    u16* agglo_bf= (u16*)(wsb + ((size_t)38<<20));
    u16* x2y_bf  = (u16*)(wsb + ((size_t)42<<20));  // y, then x2
    u16* tg_bf   = (u16*)(wsb + ((size_t)46<<20));
    u16* ygo_bf  = (u16*)(wsb + ((size_t)50<<20));
    u16* hn_bf   = (u16*)(wsb + ((size_t)54<<20));
    u16* WT      = (u16*)(wsb + ((size_t)58<<20));  // 2.62MB
    float* btab  = (float*)(wsb + ((size_t)61<<20)); // 65
    float* kvb   = btab + 128;                       // 32768
    float* ksb   = kvb + 32768;                      // 1024

    // WT sub-offsets (u16 units)
    const int WT_BIG  = 0;        // [1792][256]: q|k|v|qkv|f1
    const int WT_LO   = 458752;   // [256][256]
    const int WT_G1   = 524288;   // [256][512]
    const int WT_G2   = 655360;   // [256][256]
    const int WT_GO   = 720896;   // [256][256]
    const int WT_FF1  = 786432;   // [1024][256]
    const int WT_FF2  = 1048576;  // [256][1024]

    TransArgs ta;
    ta.d[0]  = { wq,   WT_BIG + 0,        256,  256,    0 };
    ta.d[1]  = { wk,   WT_BIG + 65536,    256,  256,   64 };
    ta.d[2]  = { wv,   WT_BIG + 131072,   256,  256,  128 };
    ta.d[3]  = { wqkv, WT_BIG + 196608,   256,  768,  192 };
    ta.d[4]  = { wf1,  WT_BIG + 393216,   256,  256,  384 };
    ta.d[5]  = { wlo,  WT_LO,             256,  256,  448 };
    ta.d[6]  = { wg1,  WT_G1,             512,  256,  512 };
    ta.d[7]  = { wg2,  WT_G2,             256,  256,  640 };
    ta.d[8]  = { wgo,  WT_GO,             256,  256,  704 };
    ta.d[9]  = { wff1, WT_FF1,            256, 1024,  768 };
    ta.d[10] = { wff2, WT_FF2,           1024,  256, 1024 };
    // transpose tiles: 1280

    const int KBIG = 1<<30;
    dim3 blk(256);

    // 1. prep: transpose + LN + bias table + kv zero
    prep_kernel<<<9669, blk, 0, stream>>>(ta, WT, x, g1, b1, h_bf,
                                          relpos_emb, we1, be1, we2, be2, btab, kvb);
    // 2. big: [nb(q|k|v) | qkv(qg|kg|vg) | gelu(f1)+bf1] = h @ WT_BIG
    mgemm<1,false,u16><<<dim3(128,14), blk, 0, stream>>>(h_bf, h_bf, KBIG, 256, WT+WT_BIG, 256, bf1, 1536, bigout, LDBIG, nullptr, nullptr);
    // 3-4. linear attention
    linstats_kernel<<<512, blk, 0, stream>>>(bigout, mask, kvb, ksb);
    linapply_kernel<<<NROWS, blk, 0, stream>>>(bigout, kvb, ksb, x2y_bf);   // y
    // 5. neighbor attention
    nattn_kernel<<<NROWS, blk, 0, stream>>>(bigout, nbr_idx, nbr_mask, rel_pos, mask, btab, agg_bf);
    // 6. dual: ygo = y@wgo ; agglo = agg@wlo + blo
    {
        DualCfg cgo = { x2y_bf, WT+WT_GO, nullptr, ygo_bf };
        DualCfg clo = { agg_bf, WT+WT_LO, blo,     agglo_bf };
        mgemm_dual<<<dim3(128,2,2), blk, 0, stream>>>(cgo, clo);
    }
    // 7. t1 = gelu([h|agglo]@wg1 + bg1)
    mgemm<1,false,u16><<<dim3(128,2), blk, 0, stream>>>(h_bf, agglo_bf, 256, 256, WT+WT_G1, 512, bg1, 0, tg_bf, 256, nullptr, nullptr);
    // 8. g = sigmoid(t1@wg2 + bg2) -> agg slot
    mgemm<2,false,u16><<<dim3(128,2), blk, 0, stream>>>(tg_bf, tg_bf, KBIG, 256, WT+WT_G2, 256, bg2, 0, agg_bf, 256, nullptr, nullptr);
    // 9. combine (+fw) -> x2 (x2y slot), hn
    combine_kernel<<<NROWS, dim3(128), 0, stream>>>(h_bf, agglo_bf, agg_bf, ygo_bf, bigout, wf2, bf2, mask, g2, b2, x2y_bf, hn_bf);
    // 10. ffn1 = gelu(hn@wff1 + bff1) -> bigout
    mgemm<1,false,u16><<<dim3(128,8), blk, 0, stream>>>(hn_bf, hn_bf, KBIG, 256, WT+WT_FF1, 256, bff1, 0, bigout, 1024, nullptr, nullptr);
    // 11. out = (x2 + ffn1@wff2 + bff2)*mf
    mgemm<0,true,float><<<dim3(128,2), blk, 0, stream>>>(bigout, bigout, KBIG, 1024, WT+WT_FF2, 1024, bff2, 0, out, 256, x2y_bf, mask);
}